// Round 6
// baseline (716.007 us; speedup 1.0000x reference)
//
#include <hip/hip_runtime.h>

#define CH 64
#define TILE 128

typedef short s16x8 __attribute__((ext_vector_type(8)));
typedef float f32x4 __attribute__((ext_vector_type(4)));

struct __attribute__((packed, aligned(4))) F4u { float x, y, z, w; };

static __device__ __forceinline__ ushort f2bf(float f) {
    union { float f; uint u; } v; v.f = f;
    const uint r = (v.u + 0x7FFFu + ((v.u >> 16) & 1u)) >> 16;
    return (ushort)r;
}

// =====================================================================
// Prepack encoder weights (5,64,64,4) [o][i][tau] -> [L][i][o][tau]
// so each (wave=16 out-ch, i) needs 64 contiguous floats -> s_load.
// =====================================================================
__global__ __launch_bounds__(256) void k_prepack_enc(
    const float* __restrict__ enc_w, float* __restrict__ encW)
{
    const int idx = blockIdx.x * 256 + threadIdx.x;   // 5*16384 = 81920
    const int tau = idx & 3;
    const int o = (idx >> 2) & 63;
    const int i = (idx >> 8) & 63;
    const int L = idx >> 14;
    encW[idx] = enc_w[(((size_t)L * 64 + o) * 64 + i) * 4 + tau];
}

// =====================================================================
// ENCODER conv (fp32): wave w -> out-ch 16w..16w+15 (weights SGPR),
// lane -> 2 positions (m0+lane, m0+64+lane), taps read direct from global.
// =====================================================================
template<bool EDGE>
__device__ __forceinline__ void enc_taps(
    const float* __restrict__ row, int p0, int Lin,
    float& t0, float& t1, float& t2, float& t3)
{
    if (!EDGE) {
        const F4u v = *(const F4u*)(row + p0);   // 4B-aligned ok
        t0 = v.x; t1 = v.y; t2 = v.z; t3 = v.w;
    } else {
        t0 = (p0 >= 0) ? row[p0] : 0.f;          // p0=-1 only at left edge
        t1 = row[p0 + 1];                         // 2m in [0, Lin-2]
        t2 = row[p0 + 2];                         // 2m+1 <= Lin-1
        t3 = (p0 + 3 < Lin) ? row[p0 + 3] : 0.f; // right edge
    }
}

template<bool EDGE>
__device__ __forceinline__ void enc_body(
    const float* __restrict__ inb, const float* __restrict__ wpk,
    const float* __restrict__ bias, float* __restrict__ out,
    int Lin, int Lout, int transpose, int b, int m0)
{
    const int tid = threadIdx.x;
    const int lane = tid & 63;
    const int wq = __builtin_amdgcn_readfirstlane(tid >> 6);
    float acc0[16], acc1[16];
#pragma unroll
    for (int oc = 0; oc < 16; ++oc) {
        const float bv = bias[16 * wq + oc];
        acc0[oc] = bv; acc1[oc] = bv;
    }
    const int p0a = 2 * (m0 + lane) - 1;
    const int p0b = p0a + 128;
    const float* wb = wpk + 64 * wq;
    for (int ii = 0; ii < 64; ++ii) {
        const float* row = inb + (size_t)ii * Lin;
        float a0, a1, a2, a3, c0, c1, c2, c3;
        enc_taps<EDGE>(row, p0a, Lin, a0, a1, a2, a3);
        enc_taps<EDGE>(row, p0b, Lin, c0, c1, c2, c3);
        const float* wp = wb + ii * 256;          // uniform -> s_load
#pragma unroll
        for (int oc = 0; oc < 16; ++oc) {
            const float4 wv = *(const float4*)(wp + 4 * oc);
            acc0[oc] += wv.x * a0 + wv.y * a1 + wv.z * a2 + wv.w * a3;
            acc1[oc] += wv.x * c0 + wv.y * c1 + wv.z * c2 + wv.w * c3;
        }
    }
    if (!transpose) {
#pragma unroll
        for (int oc = 0; oc < 16; ++oc) {
            float* ob = out + ((size_t)b * CH + 16 * wq + oc) * Lout + m0 + lane;
            ob[0]  = fmaxf(acc0[oc], 0.f);
            ob[64] = fmaxf(acc1[oc], 0.f);
        }
    } else {
        // z_e layout [(b*Lout + m)*64 + o]
        float* ob0 = out + ((size_t)b * Lout + m0 + lane) * CH + 16 * wq;
        float* ob1 = ob0 + (size_t)64 * CH;
#pragma unroll
        for (int c = 0; c < 4; ++c) {
            float4 v0, v1;
            v0.x = fmaxf(acc0[4*c+0], 0.f); v0.y = fmaxf(acc0[4*c+1], 0.f);
            v0.z = fmaxf(acc0[4*c+2], 0.f); v0.w = fmaxf(acc0[4*c+3], 0.f);
            *(float4*)(ob0 + 4 * c) = v0;
            v1.x = fmaxf(acc1[4*c+0], 0.f); v1.y = fmaxf(acc1[4*c+1], 0.f);
            v1.z = fmaxf(acc1[4*c+2], 0.f); v1.w = fmaxf(acc1[4*c+3], 0.f);
            *(float4*)(ob1 + 4 * c) = v1;
        }
    }
}

__global__ __launch_bounds__(256) void k_enc_conv(
    const float* __restrict__ in, const float* __restrict__ wpk,
    const float* __restrict__ bias, float* __restrict__ out,
    int Lin, int Lout, int transpose)
{
    const int m0 = blockIdx.x * TILE;
    const int b = blockIdx.y;
    const float* inb = in + (size_t)b * CH * Lin;
    if (blockIdx.x == 0 || blockIdx.x == gridDim.x - 1)
        enc_body<true>(inb, wpk, bias, out, Lin, Lout, transpose, b, m0);
    else
        enc_body<false>(inb, wpk, bias, out, Lin, Lout, transpose, b, m0);
}

// fused conv0 (1->64) + conv1 (64->64); e0 tile in LDS (zero-padded),
// conv1 accum with SGPR weights + conflict-free b64 lane reads.
__global__ __launch_bounds__(256) void k_enc01(
    const float* __restrict__ x, const float* __restrict__ w0,
    const float* __restrict__ b0, const float* __restrict__ wpk0,
    const float* __restrict__ b1, float* __restrict__ out)
{
    __shared__ float xl[520];
    __shared__ float e0s[32][264];
    const int m0 = blockIdx.x * TILE;
    const int b = blockIdx.y;
    const int tid = threadIdx.x;
    const int lane = tid & 63;
    const int wq = __builtin_amdgcn_readfirstlane(tid >> 6);
    const float* xb = x + (size_t)b * 65536;
    const int x0i = 4 * m0 - 3;
    for (int xi = tid; xi < 518; xi += 256) {
        const int q = x0i + xi;
        xl[xi] = (q >= 0 && q < 65536) ? xb[q] : 0.f;
    }
    float acc0[16], acc1[16];
#pragma unroll
    for (int oc = 0; oc < 16; ++oc) {
        const float bv = b1[16 * wq + oc];
        acc0[oc] = bv; acc1[oc] = bv;
    }
    const int r = tid >> 3;
    const int oct = tid & 7;
    const int pbase = 2 * m0 - 1;      // e0-pos of pl=0; e0 length = 32768
    __syncthreads();
    for (int half = 0; half < 2; ++half) {
        {
            const int i = half * 32 + r;
            const float4 wv = *(const float4*)(w0 + i * 4);
            const float bv = b0[i];
            for (int t = 0; t < 33; ++t) {
                const int pl = oct * 33 + t;
                if (pl < 258) {
                    const int pe = pbase + pl;
                    const float* xp = xl + 2 * pl;
                    const float v = wv.x * xp[0] + wv.y * xp[1] + wv.z * xp[2] + wv.w * xp[3] + bv;
                    e0s[r][pl] = (pe >= 0 && pe < 32768) ? fmaxf(v, 0.f) : 0.f;
                }
            }
        }
        __syncthreads();
        const float* wb = wpk0 + (size_t)(32 * half) * 256 + 64 * wq;
        for (int ii = 0; ii < 32; ++ii) {
            const float* row = e0s[ii];
            const float2 xa = *(const float2*)(row + 2 * lane);
            const float2 xb2 = *(const float2*)(row + 2 * lane + 2);
            const float2 xc = *(const float2*)(row + 2 * lane + 128);
            const float2 xd = *(const float2*)(row + 2 * lane + 130);
            const float* wp = wb + ii * 256;
#pragma unroll
            for (int oc = 0; oc < 16; ++oc) {
                const float4 wv = *(const float4*)(wp + 4 * oc);
                acc0[oc] += wv.x * xa.x + wv.y * xa.y + wv.z * xb2.x + wv.w * xb2.y;
                acc1[oc] += wv.x * xc.x + wv.y * xc.y + wv.z * xd.x + wv.w * xd.y;
            }
        }
        __syncthreads();
    }
#pragma unroll
    for (int oc = 0; oc < 16; ++oc) {
        float* ob = out + ((size_t)b * CH + 16 * wq + oc) * 16384 + m0 + lane;
        ob[0]  = fmaxf(acc0[oc], 0.f);
        ob[64] = fmaxf(acc1[oc], 0.f);
    }
}

// =====================================================================
// VQ: 512 threads = 8 waves; wave w -> codes [128w,128w+128) (SGPR
// broadcast codebook); lane -> token t0+lane with -2z in VGPRs.
// dist = |c|^2 + (-2z)·c ; first-min tie-break preserved.
// =====================================================================
__global__ __launch_bounds__(512) void k_vq(
    const float* __restrict__ z, const float* __restrict__ cb,
    float* __restrict__ idsf, float* __restrict__ g)
{
    __shared__ float c2s[1024];
    __shared__ float rval[8][64];
    __shared__ int   ridx[8][64];
    __shared__ int   widx[64];
    const int t0 = blockIdx.x * 64;
    const int tid = threadIdx.x;
    const int lane = tid & 63;
    const int wv = __builtin_amdgcn_readfirstlane(tid >> 6);

    // |c|^2 for all 1024 codes (2 per thread)
    for (int c = tid; c < 1024; c += 512) {
        const float* cp = cb + (size_t)c * 64;
        float s0 = 0.f, s1 = 0.f, s2 = 0.f, s3 = 0.f;
#pragma unroll
        for (int d = 0; d < 64; d += 4) {
            const float4 v = *(const float4*)(cp + d);
            s0 += v.x * v.x; s1 += v.y * v.y; s2 += v.z * v.z; s3 += v.w * v.w;
        }
        c2s[c] = (s0 + s1) + (s2 + s3);
    }
    // -2z for this lane's token, in registers
    float pz[64];
    {
        const float* zp = z + (size_t)(t0 + lane) * 64;
#pragma unroll
        for (int d = 0; d < 64; d += 4) {
            const float4 v = *(const float4*)(zp + d);
            pz[d] = -2.f * v.x; pz[d + 1] = -2.f * v.y;
            pz[d + 2] = -2.f * v.z; pz[d + 3] = -2.f * v.w;
        }
    }
    __syncthreads();
    float best = 3.0e38f; int bidx = 0;
    const int cbase = wv * 128;
    for (int cc = 0; cc < 128; ++cc) {
        const int code = cbase + cc;
        const float* cp = cb + (size_t)code * 64;   // uniform -> s_load
        float a0 = 0.f, a1 = 0.f, a2 = 0.f, a3 = 0.f;
#pragma unroll
        for (int d = 0; d < 64; d += 4) {
            a0 += cp[d] * pz[d];
            a1 += cp[d + 1] * pz[d + 1];
            a2 += cp[d + 2] * pz[d + 2];
            a3 += cp[d + 3] * pz[d + 3];
        }
        const float dist = c2s[code] + ((a0 + a1) + (a2 + a3));
        if (dist < best) { best = dist; bidx = code; }
    }
    rval[wv][lane] = best; ridx[wv][lane] = bidx;
    __syncthreads();
    if (tid < 64) {
        float bv = rval[0][tid]; int bi = ridx[0][tid];
#pragma unroll
        for (int k2 = 1; k2 < 8; ++k2) {
            const float v = rval[k2][tid];
            if (v < bv) { bv = v; bi = ridx[k2][tid]; }  // slices ascending
        }
        widx[tid] = bi;
        idsf[t0 + tid] = (float)bi;
    }
    __syncthreads();
    const int bb = t0 >> 10;
    const int mb = t0 & 1023;
    for (int e = tid; e < 4096; e += 512) {
        const int tok = e & 63;
        const int d = e >> 6;
        g[((size_t)bb * CH + d) * 1024 + mb + tok] = cb[(size_t)widx[tok] * 64 + d];
    }
}

// =====================================================================
// DECODER: bf16 MFMA convT (unchanged from round 4/5)
// =====================================================================
__global__ __launch_bounds__(256) void k_prepack(
    const float* __restrict__ dec_w, ushort* __restrict__ Afrag)
{
    const int idx = blockIdx.x * 256 + threadIdx.x;   // 5*16384 = 81920
    const int j    = idx & 7;
    const int lane = (idx >> 3) & 63;
    const int kt   = (idx >> 9) & 3;
    const int m    = (idx >> 11) & 3;
    const int p    = (idx >> 13) & 1;
    const int L    = idx >> 14;
    const int o = m * 16 + (lane & 15);
    const int k = kt * 32 + (lane >> 4) * 8 + j;
    const int i = k >> 1;
    const int t = k & 1;
    const int tau = p ? (t ? 0 : 2) : (t ? 3 : 1);
    const float v = dec_w[(((size_t)L * 64 + i) * 64 + o) * 4 + tau];
    Afrag[idx] = f2bf(v);
}

__global__ __launch_bounds__(256) void k_dec_mfma(
    const float* __restrict__ X, const ushort* __restrict__ Afrag,
    const float* __restrict__ bias, float* __restrict__ Y, int Lin)
{
    __shared__ __align__(16) ushort BE[64 * 136];
    __shared__ __align__(16) ushort BO[64 * 136];
    const int u0 = blockIdx.x * 64;
    const int b  = blockIdx.y;
    const int tid = threadIdx.x;
    const int Lout = Lin * 2;

    uint* BEw = (uint*)BE;
    uint* BOw = (uint*)BO;
#pragma unroll
    for (int s = 0; s < 4; ++s) {
        const int e = tid + 256 * s;
        const int ml = e & 63;
        const int i4 = (e >> 6) * 4;
        const int u = u0 + ml;
        const float* xc = X + ((size_t)b * 64 + i4) * Lin + u;
        uint eD[4], oD[4];
#pragma unroll
        for (int r = 0; r < 4; ++r) {
            const float* xr = xc + (size_t)r * Lin;
            const float x0 = xr[0];
            const float xm = (u > 0) ? xr[-1] : 0.f;
            const float xp = (u + 1 < Lin) ? xr[1] : 0.f;
            const uint b0 = f2bf(x0);
            eD[r] = b0 | ((uint)f2bf(xm) << 16);
            oD[r] = b0 | ((uint)f2bf(xp) << 16);
        }
        *(uint4*)&BEw[ml * 68 + i4] = make_uint4(eD[0], eD[1], eD[2], eD[3]);
        *(uint4*)&BOw[ml * 68 + i4] = make_uint4(oD[0], oD[1], oD[2], oD[3]);
    }
    __syncthreads();

    const int wave = tid >> 6, lane = tid & 63;
    const int col = lane & 15, kg = lane >> 4;
    const int ml = wave * 16 + col;
    const s16x8* BEf = (const s16x8*)&BE[ml * 136 + kg * 8];
    const s16x8* BOf = (const s16x8*)&BO[ml * 136 + kg * 8];
    s16x8 be[4], bo[4];
#pragma unroll
    for (int kt = 0; kt < 4; ++kt) { be[kt] = BEf[4 * kt]; bo[kt] = BOf[4 * kt]; }

    const s16x8* Af = (const s16x8*)Afrag;
    const int n2 = 2 * (u0 + ml);
#pragma unroll
    for (int m = 0; m < 4; ++m) {
        const s16x8* Ae = Af + ((0 * 4 + m) * 4) * 64 + lane;
        const s16x8* Ao = Af + ((1 * 4 + m) * 4) * 64 + lane;
        f32x4 accE = {0.f, 0.f, 0.f, 0.f};
        f32x4 accO = {0.f, 0.f, 0.f, 0.f};
#pragma unroll
        for (int kt = 0; kt < 4; ++kt) {
            accE = __builtin_amdgcn_mfma_f32_16x16x32_bf16(Ae[kt * 64], be[kt], accE, 0, 0, 0);
            accO = __builtin_amdgcn_mfma_f32_16x16x32_bf16(Ao[kt * 64], bo[kt], accO, 0, 0, 0);
        }
        const float4 bm4 = *(const float4*)(bias + m * 16 + kg * 4);
        float* yo = Y + ((size_t)b * 64 + m * 16 + kg * 4) * Lout + n2;
        const float bb[4] = {bm4.x, bm4.y, bm4.z, bm4.w};
#pragma unroll
        for (int r = 0; r < 4; ++r) {
            float2 v;
            v.x = fmaxf(accE[r] + bb[r], 0.f);
            v.y = fmaxf(accO[r] + bb[r], 0.f);
            *(float2*)(yo + (size_t)r * Lout) = v;
        }
    }
}

__global__ __launch_bounds__(256) void k_last(
    const float* __restrict__ d4, const float* __restrict__ wl,
    const float* __restrict__ blp, float* __restrict__ y, int bbase)
{
    __shared__ float dl[64][260];
    const int n0 = blockIdx.x * 512;
    const int bl = blockIdx.y;
    const int v0 = n0 >> 1;
    const int tid = threadIdx.x;
    const float* db = d4 + (size_t)bl * 64 * 32768;
    for (int e = tid; e < 64 * 258; e += 256) {
        const int i = e / 258;
        const int pl = e - i * 258;
        const int v = v0 - 1 + pl;
        dl[i][pl] = (v >= 0 && v < 32768) ? db[(size_t)i * 32768 + v] : 0.f;
    }
    __syncthreads();
    const int pl = tid + 1;
    float accE = blp[0], accO = blp[0];
    for (int i = 0; i < 64; ++i) {
        const float4 wv = *(const float4*)(wl + i * 4);
        const float xm = dl[i][pl - 1];
        const float x0 = dl[i][pl];
        const float xp = dl[i][pl + 1];
        accE += wv.y * x0 + wv.w * xm;
        accO += wv.z * x0 + wv.x * xp;
    }
    float* yb = y + (size_t)(bbase + bl) * 65536 + n0 + 2 * tid;
    yb[0] = accE;
    yb[1] = accO;
}

extern "C" void kernel_launch(void* const* d_in, const int* in_sizes, int n_in,
                              void* d_out, int out_size, void* d_ws, size_t ws_size,
                              hipStream_t stream) {
    const float* x      = (const float*)d_in[0];
    const float* enc_w0 = (const float*)d_in[1];
    const float* enc_w  = (const float*)d_in[2];   // (5,64,64,4)
    const float* enc_b  = (const float*)d_in[3];   // (6,64)
    const float* cb     = (const float*)d_in[4];   // (1024,64)
    const float* dec_w  = (const float*)d_in[5];   // (5,64,64,4) [in][out][k]
    const float* dec_wl = (const float*)d_in[6];   // (64,1,4)
    const float* dec_b  = (const float*)d_in[7];   // (5,64)
    const float* dec_bl = (const float*)d_in[8];   // (1,)
    float* y    = (float*)d_out;                   // (16,1,65536)
    float* z_e  = y + 1048576;                     // (16384,64)
    float* idsf = y + 2097152;                     // (16384,)

    // workspace overlay: A = 16.7M floats (67MB), Bf = 8.4M floats (33.6MB)
    float* A  = (float*)d_ws;
    float* Bf = A + 16777216;

    // Scratch in y batches 14-15 (dead until final k_last q=3 overwrites):
    // encW: 81920 floats; Afrag: 81920 ushorts (40960 floats). Total 122880
    // floats <= 131072 available.
    float*  encW  = y + 14 * 65536;
    ushort* Afrag = (ushort*)(encW + 81920);

    k_prepack_enc<<<dim3(320), 256, 0, stream>>>(enc_w, encW);
    k_prepack<<<dim3(320), 256, 0, stream>>>(dec_w, Afrag);

    // encoder (fp32, SGPR weights, global-direct taps)
    k_enc01<<<dim3(128, 16), 256, 0, stream>>>(x, enc_w0, enc_b, encW, enc_b + 64, A);
    k_enc_conv<<<dim3(64, 16), 256, 0, stream>>>(A,  encW + 1 * 16384, enc_b + 2 * 64, Bf, 16384, 8192, 0);
    k_enc_conv<<<dim3(32, 16), 256, 0, stream>>>(Bf, encW + 2 * 16384, enc_b + 3 * 64, A,  8192,  4096, 0);
    k_enc_conv<<<dim3(16, 16), 256, 0, stream>>>(A,  encW + 3 * 16384, enc_b + 4 * 64, Bf, 4096,  2048, 0);
    k_enc_conv<<<dim3(8, 16),  256, 0, stream>>>(Bf, encW + 4 * 16384, enc_b + 5 * 64, z_e, 2048, 1024, 1);
    // vector quantize -> g in A
    k_vq<<<256, 512, 0, stream>>>(z_e, cb, idsf, A);

    // decoder (bf16 MFMA)
    k_dec_mfma<<<dim3(16, 16),  256, 0, stream>>>(A,  Afrag + 0 * 16384, dec_b + 0 * 64, Bf, 1024);
    k_dec_mfma<<<dim3(32, 16),  256, 0, stream>>>(Bf, Afrag + 1 * 16384, dec_b + 1 * 64, A,  2048);
    k_dec_mfma<<<dim3(64, 16),  256, 0, stream>>>(A,  Afrag + 2 * 16384, dec_b + 2 * 64, Bf, 4096);
    k_dec_mfma<<<dim3(128, 16), 256, 0, stream>>>(Bf, Afrag + 3 * 16384, dec_b + 3 * 64, A,  8192);
    for (int q = 0; q < 4; ++q) {
        k_dec_mfma<<<dim3(256, 4), 256, 0, stream>>>(A + (size_t)q * 4 * 64 * 16384,
                                                     Afrag + 4 * 16384, dec_b + 4 * 64, Bf, 16384);
        k_last<<<dim3(128, 4), 256, 0, stream>>>(Bf, dec_wl, dec_bl, y, q * 4);
    }
}

// Round 7
// 646.263 us; speedup vs baseline: 1.1079x; 1.1079x over previous
//
#include <hip/hip_runtime.h>

#define CH 64
#define TILE 128

typedef short s16x8 __attribute__((ext_vector_type(8)));
typedef float f32x4 __attribute__((ext_vector_type(4)));

static __device__ __forceinline__ ushort f2bf(float f) {
    union { float f; uint u; } v; v.f = f;
    const uint r = (v.u + 0x7FFFu + ((v.u >> 16) & 1u)) >> 16;
    return (ushort)r;
}

// =====================================================================
// Prepack encoder weights (5,64,64,4) [o][i][tau] -> [L][i][o][tau]:
// per (i, og) the 16 floats {o=og*4..og*4+3, tau} are contiguous.
// =====================================================================
__global__ __launch_bounds__(256) void k_prepack_enc(
    const float* __restrict__ enc_w, float* __restrict__ encW)
{
    const int idx = blockIdx.x * 256 + threadIdx.x;   // 5*16384 = 81920
    const int tau = idx & 3;
    const int o = (idx >> 2) & 63;
    const int i = (idx >> 8) & 63;
    const int L = idx >> 14;
    encW[idx] = enc_w[(((size_t)L * 64 + o) * 64 + i) * 4 + tau];
}

// =====================================================================
// ENCODER (fp32): 128-pos tile, 256 threads, LDS-staged input.
// inT row[pl] = input pos p = 2*m0 - 1 + pl, pl in [0,258).
// Thread: og = tid>>4 -> out-ch og*4..og*4+3 ; pg = tid&15 ->
// position pairs ml = 2*pg + 32*j (+1), j=0..3.
// LDS reads: float2 at dword 4pg+64j (+2,+4): 2-way bank alias = free,
// 4-way same-address broadcast across og = free.
// =====================================================================
__device__ __forceinline__ void stage_half(
    const float* __restrict__ inb, float (*inT)[264], int half,
    int m0, int Lin, int tid)
{
    const int r = tid >> 3;            // 0..31
    const int i = half * 32 + r;
    const int seg = tid & 7;
    // interior pl = 1 + 32*seg + 4t : p = 2*m0 + 32*seg + 4t, in bounds
    const float* src = inb + (size_t)i * Lin + 2 * m0 + 32 * seg;
    float* dst = inT[r] + 1 + 32 * seg;
#pragma unroll
    for (int t = 0; t < 8; ++t) {
        const float4 v = *(const float4*)(src + 4 * t);
        float* d = dst + 4 * t;
        d[0] = v.x;
        *(float2*)(d + 1) = make_float2(v.y, v.z);
        d[3] = v.w;
    }
    if (tid < 64) {                    // edges pl=0 and pl=257
        const int rr = tid & 31, side = tid >> 5;
        const int pl = side ? 257 : 0;
        const int p = 2 * m0 - 1 + pl;
        inT[rr][pl] = (p >= 0 && p < Lin) ? inb[(size_t)(half * 32 + rr) * Lin + p] : 0.f;
    }
}

__device__ __forceinline__ void conv_accum_half(
    const float (*inT)[264], const float* __restrict__ wpk, int ibase,
    float acc[4][8], int og, int pg)
{
    const float* wI = wpk + og * 16 + (size_t)ibase * 256;
    for (int ii = 0; ii < 32; ++ii) {
        const float* wp = wI + ii * 256;
        const float4 w0 = *(const float4*)(wp + 0);
        const float4 w1 = *(const float4*)(wp + 4);
        const float4 w2 = *(const float4*)(wp + 8);
        const float4 w3 = *(const float4*)(wp + 12);
        const float* row = inT[ii];
#pragma unroll
        for (int j = 0; j < 4; ++j) {
            const int base = 4 * pg + 64 * j;
            const float2 xa = *(const float2*)(row + base);
            const float2 xb = *(const float2*)(row + base + 2);
            const float2 xc = *(const float2*)(row + base + 4);
            acc[0][2*j]   += w0.x * xa.x + w0.y * xa.y + w0.z * xb.x + w0.w * xb.y;
            acc[1][2*j]   += w1.x * xa.x + w1.y * xa.y + w1.z * xb.x + w1.w * xb.y;
            acc[2][2*j]   += w2.x * xa.x + w2.y * xa.y + w2.z * xb.x + w2.w * xb.y;
            acc[3][2*j]   += w3.x * xa.x + w3.y * xa.y + w3.z * xb.x + w3.w * xb.y;
            acc[0][2*j+1] += w0.x * xb.x + w0.y * xb.y + w0.z * xc.x + w0.w * xc.y;
            acc[1][2*j+1] += w1.x * xb.x + w1.y * xb.y + w1.z * xc.x + w1.w * xc.y;
            acc[2][2*j+1] += w2.x * xb.x + w2.y * xb.y + w2.z * xc.x + w2.w * xc.y;
            acc[3][2*j+1] += w3.x * xb.x + w3.y * xb.y + w3.z * xc.x + w3.w * xc.y;
        }
    }
}

__device__ __forceinline__ void conv_epilogue(
    float acc[4][8], float* __restrict__ out,
    int b, int m0, int Lout, int transpose, int og, int pg)
{
    if (!transpose) {
#pragma unroll
        for (int oo = 0; oo < 4; ++oo) {
            float* ob = out + ((size_t)b * CH + og * 4 + oo) * Lout + m0 + 2 * pg;
#pragma unroll
            for (int j = 0; j < 4; ++j) {
                float2 v;
                v.x = fmaxf(acc[oo][2*j], 0.f);
                v.y = fmaxf(acc[oo][2*j+1], 0.f);
                *(float2*)(ob + 32 * j) = v;
            }
        }
    } else {
        // z_e layout [(b*Lout + m)*64 + o]
#pragma unroll
        for (int j = 0; j < 4; ++j)
#pragma unroll
            for (int h = 0; h < 2; ++h) {
                const int ml = 2 * pg + 32 * j + h;
                float* ob = out + ((size_t)b * Lout + m0 + ml) * CH + og * 4;
                float4 v;
                v.x = fmaxf(acc[0][2*j+h], 0.f);
                v.y = fmaxf(acc[1][2*j+h], 0.f);
                v.z = fmaxf(acc[2][2*j+h], 0.f);
                v.w = fmaxf(acc[3][2*j+h], 0.f);
                *(float4*)ob = v;
            }
    }
}

__global__ __launch_bounds__(256) void k_enc_conv(
    const float* __restrict__ in, const float* __restrict__ wpk,
    const float* __restrict__ bias, float* __restrict__ out,
    int Lin, int Lout, int transpose)
{
    __shared__ float inT[32][264];
    const int m0 = blockIdx.x * TILE;
    const int b = blockIdx.y;
    const int tid = threadIdx.x;
    const int og = tid >> 4, pg = tid & 15;
    const float* inb = in + (size_t)b * CH * Lin;
    float acc[4][8];
#pragma unroll
    for (int oo = 0; oo < 4; ++oo) {
        const float bv = bias[og * 4 + oo];
#pragma unroll
        for (int j = 0; j < 8; ++j) acc[oo][j] = bv;
    }
    stage_half(inb, inT, 0, m0, Lin, tid);
    __syncthreads();
    conv_accum_half(inT, wpk, 0, acc, og, pg);
    __syncthreads();
    stage_half(inb, inT, 1, m0, Lin, tid);
    __syncthreads();
    conv_accum_half(inT, wpk, 32, acc, og, pg);
    conv_epilogue(acc, out, b, m0, Lout, transpose, og, pg);
}

// fused conv0 (1->64) + conv1 (64->64)
__global__ __launch_bounds__(256) void k_enc01(
    const float* __restrict__ x, const float* __restrict__ w0,
    const float* __restrict__ b0, const float* __restrict__ wpk0,
    const float* __restrict__ b1, float* __restrict__ out)
{
    __shared__ float xl[520];
    __shared__ float e0s[32][264];
    const int m0 = blockIdx.x * TILE;
    const int b = blockIdx.y;
    const int tid = threadIdx.x;
    const int og = tid >> 4, pg = tid & 15;
    const float* xb = x + (size_t)b * 65536;
    const int x0i = 4 * m0 - 3;
    for (int xi = tid; xi < 518; xi += 256) {
        const int q = x0i + xi;
        xl[xi] = (q >= 0 && q < 65536) ? xb[q] : 0.f;
    }
    float acc[4][8];
#pragma unroll
    for (int oo = 0; oo < 4; ++oo) {
        const float bv = b1[og * 4 + oo];
#pragma unroll
        for (int j = 0; j < 8; ++j) acc[oo][j] = bv;
    }
    const int r = tid >> 3;            // e0 row worker 0..31
    const int oct = tid & 7;
    const int pbase = 2 * m0 - 1;      // e0-pos of pl=0; e0 length = 32768
    __syncthreads();
    for (int half = 0; half < 2; ++half) {
        {
            const int i = half * 32 + r;
            const float4 wv = *(const float4*)(w0 + i * 4);
            const float bv = b0[i];
            for (int t = 0; t < 33; ++t) {
                const int pl = oct * 33 + t;
                if (pl < 258) {
                    const int pe = pbase + pl;
                    const float* xp = xl + 2 * pl;
                    const float v = wv.x * xp[0] + wv.y * xp[1] + wv.z * xp[2] + wv.w * xp[3] + bv;
                    e0s[r][pl] = (pe >= 0 && pe < 32768) ? fmaxf(v, 0.f) : 0.f;
                }
            }
        }
        __syncthreads();
        conv_accum_half(e0s, wpk0, half * 32, acc, og, pg);
        __syncthreads();
    }
    conv_epilogue(acc, out, b, m0, 16384, 0, og, pg);
}

// =====================================================================
// VQ (unchanged from round 6): wave -> 128-code slice (SGPR broadcast),
// lane -> token with -2z in VGPRs.
// =====================================================================
__global__ __launch_bounds__(512) void k_vq(
    const float* __restrict__ z, const float* __restrict__ cb,
    float* __restrict__ idsf, float* __restrict__ g)
{
    __shared__ float c2s[1024];
    __shared__ float rval[8][64];
    __shared__ int   ridx[8][64];
    __shared__ int   widx[64];
    const int t0 = blockIdx.x * 64;
    const int tid = threadIdx.x;
    const int lane = tid & 63;
    const int wv = __builtin_amdgcn_readfirstlane(tid >> 6);

    for (int c = tid; c < 1024; c += 512) {
        const float* cp = cb + (size_t)c * 64;
        float s0 = 0.f, s1 = 0.f, s2 = 0.f, s3 = 0.f;
#pragma unroll
        for (int d = 0; d < 64; d += 4) {
            const float4 v = *(const float4*)(cp + d);
            s0 += v.x * v.x; s1 += v.y * v.y; s2 += v.z * v.z; s3 += v.w * v.w;
        }
        c2s[c] = (s0 + s1) + (s2 + s3);
    }
    float pz[64];
    {
        const float* zp = z + (size_t)(t0 + lane) * 64;
#pragma unroll
        for (int d = 0; d < 64; d += 4) {
            const float4 v = *(const float4*)(zp + d);
            pz[d] = -2.f * v.x; pz[d + 1] = -2.f * v.y;
            pz[d + 2] = -2.f * v.z; pz[d + 3] = -2.f * v.w;
        }
    }
    __syncthreads();
    float best = 3.0e38f; int bidx = 0;
    const int cbase = wv * 128;
    for (int cc = 0; cc < 128; ++cc) {
        const int code = cbase + cc;
        const float* cp = cb + (size_t)code * 64;   // uniform -> s_load
        float a0 = 0.f, a1 = 0.f, a2 = 0.f, a3 = 0.f;
#pragma unroll
        for (int d = 0; d < 64; d += 4) {
            a0 += cp[d] * pz[d];
            a1 += cp[d + 1] * pz[d + 1];
            a2 += cp[d + 2] * pz[d + 2];
            a3 += cp[d + 3] * pz[d + 3];
        }
        const float dist = c2s[code] + ((a0 + a1) + (a2 + a3));
        if (dist < best) { best = dist; bidx = code; }
    }
    rval[wv][lane] = best; ridx[wv][lane] = bidx;
    __syncthreads();
    if (tid < 64) {
        float bv = rval[0][tid]; int bi = ridx[0][tid];
#pragma unroll
        for (int k2 = 1; k2 < 8; ++k2) {
            const float v = rval[k2][tid];
            if (v < bv) { bv = v; bi = ridx[k2][tid]; }  // slices ascending
        }
        widx[tid] = bi;
        idsf[t0 + tid] = (float)bi;
    }
    __syncthreads();
    const int bb = t0 >> 10;
    const int mb = t0 & 1023;
    for (int e = tid; e < 4096; e += 512) {
        const int tok = e & 63;
        const int d = e >> 6;
        g[((size_t)bb * CH + d) * 1024 + mb + tok] = cb[(size_t)widx[tok] * 64 + d];
    }
}

// =====================================================================
// DECODER: bf16 MFMA convT (unchanged)
// =====================================================================
__global__ __launch_bounds__(256) void k_prepack(
    const float* __restrict__ dec_w, ushort* __restrict__ Afrag)
{
    const int idx = blockIdx.x * 256 + threadIdx.x;   // 5*16384 = 81920
    const int j    = idx & 7;
    const int lane = (idx >> 3) & 63;
    const int kt   = (idx >> 9) & 3;
    const int m    = (idx >> 11) & 3;
    const int p    = (idx >> 13) & 1;
    const int L    = idx >> 14;
    const int o = m * 16 + (lane & 15);
    const int k = kt * 32 + (lane >> 4) * 8 + j;
    const int i = k >> 1;
    const int t = k & 1;
    const int tau = p ? (t ? 0 : 2) : (t ? 3 : 1);
    const float v = dec_w[(((size_t)L * 64 + i) * 64 + o) * 4 + tau];
    Afrag[idx] = f2bf(v);
}

__global__ __launch_bounds__(256) void k_dec_mfma(
    const float* __restrict__ X, const ushort* __restrict__ Afrag,
    const float* __restrict__ bias, float* __restrict__ Y, int Lin)
{
    __shared__ __align__(16) ushort BE[64 * 136];
    __shared__ __align__(16) ushort BO[64 * 136];
    const int u0 = blockIdx.x * 64;
    const int b  = blockIdx.y;
    const int tid = threadIdx.x;
    const int Lout = Lin * 2;

    uint* BEw = (uint*)BE;
    uint* BOw = (uint*)BO;
#pragma unroll
    for (int s = 0; s < 4; ++s) {
        const int e = tid + 256 * s;
        const int ml = e & 63;
        const int i4 = (e >> 6) * 4;
        const int u = u0 + ml;
        const float* xc = X + ((size_t)b * 64 + i4) * Lin + u;
        uint eD[4], oD[4];
#pragma unroll
        for (int r = 0; r < 4; ++r) {
            const float* xr = xc + (size_t)r * Lin;
            const float x0 = xr[0];
            const float xm = (u > 0) ? xr[-1] : 0.f;
            const float xp = (u + 1 < Lin) ? xr[1] : 0.f;
            const uint b0 = f2bf(x0);
            eD[r] = b0 | ((uint)f2bf(xm) << 16);
            oD[r] = b0 | ((uint)f2bf(xp) << 16);
        }
        *(uint4*)&BEw[ml * 68 + i4] = make_uint4(eD[0], eD[1], eD[2], eD[3]);
        *(uint4*)&BOw[ml * 68 + i4] = make_uint4(oD[0], oD[1], oD[2], oD[3]);
    }
    __syncthreads();

    const int wave = tid >> 6, lane = tid & 63;
    const int col = lane & 15, kg = lane >> 4;
    const int ml = wave * 16 + col;
    const s16x8* BEf = (const s16x8*)&BE[ml * 136 + kg * 8];
    const s16x8* BOf = (const s16x8*)&BO[ml * 136 + kg * 8];
    s16x8 be[4], bo[4];
#pragma unroll
    for (int kt = 0; kt < 4; ++kt) { be[kt] = BEf[4 * kt]; bo[kt] = BOf[4 * kt]; }

    const s16x8* Af = (const s16x8*)Afrag;
    const int n2 = 2 * (u0 + ml);
#pragma unroll
    for (int m = 0; m < 4; ++m) {
        const s16x8* Ae = Af + ((0 * 4 + m) * 4) * 64 + lane;
        const s16x8* Ao = Af + ((1 * 4 + m) * 4) * 64 + lane;
        f32x4 accE = {0.f, 0.f, 0.f, 0.f};
        f32x4 accO = {0.f, 0.f, 0.f, 0.f};
#pragma unroll
        for (int kt = 0; kt < 4; ++kt) {
            accE = __builtin_amdgcn_mfma_f32_16x16x32_bf16(Ae[kt * 64], be[kt], accE, 0, 0, 0);
            accO = __builtin_amdgcn_mfma_f32_16x16x32_bf16(Ao[kt * 64], bo[kt], accO, 0, 0, 0);
        }
        const float4 bm4 = *(const float4*)(bias + m * 16 + kg * 4);
        float* yo = Y + ((size_t)b * 64 + m * 16 + kg * 4) * Lout + n2;
        const float bb[4] = {bm4.x, bm4.y, bm4.z, bm4.w};
#pragma unroll
        for (int r = 0; r < 4; ++r) {
            float2 v;
            v.x = fmaxf(accE[r] + bb[r], 0.f);
            v.y = fmaxf(accO[r] + bb[r], 0.f);
            *(float2*)(yo + (size_t)r * Lout) = v;
        }
    }
}

__global__ __launch_bounds__(256) void k_last(
    const float* __restrict__ d4, const float* __restrict__ wl,
    const float* __restrict__ blp, float* __restrict__ y, int bbase)
{
    __shared__ float dl[64][260];
    const int n0 = blockIdx.x * 512;
    const int bl = blockIdx.y;
    const int v0 = n0 >> 1;
    const int tid = threadIdx.x;
    const float* db = d4 + (size_t)bl * 64 * 32768;
    for (int e = tid; e < 64 * 258; e += 256) {
        const int i = e / 258;
        const int pl = e - i * 258;
        const int v = v0 - 1 + pl;
        dl[i][pl] = (v >= 0 && v < 32768) ? db[(size_t)i * 32768 + v] : 0.f;
    }
    __syncthreads();
    const int pl = tid + 1;
    float accE = blp[0], accO = blp[0];
    for (int i = 0; i < 64; ++i) {
        const float4 wv = *(const float4*)(wl + i * 4);
        const float xm = dl[i][pl - 1];
        const float x0 = dl[i][pl];
        const float xp = dl[i][pl + 1];
        accE += wv.y * x0 + wv.w * xm;
        accO += wv.z * x0 + wv.x * xp;
    }
    float* yb = y + (size_t)(bbase + bl) * 65536 + n0 + 2 * tid;
    yb[0] = accE;
    yb[1] = accO;
}

extern "C" void kernel_launch(void* const* d_in, const int* in_sizes, int n_in,
                              void* d_out, int out_size, void* d_ws, size_t ws_size,
                              hipStream_t stream) {
    const float* x      = (const float*)d_in[0];
    const float* enc_w0 = (const float*)d_in[1];
    const float* enc_w  = (const float*)d_in[2];   // (5,64,64,4)
    const float* enc_b  = (const float*)d_in[3];   // (6,64)
    const float* cb     = (const float*)d_in[4];   // (1024,64)
    const float* dec_w  = (const float*)d_in[5];   // (5,64,64,4) [in][out][k]
    const float* dec_wl = (const float*)d_in[6];   // (64,1,4)
    const float* dec_b  = (const float*)d_in[7];   // (5,64)
    const float* dec_bl = (const float*)d_in[8];   // (1,)
    float* y    = (float*)d_out;                   // (16,1,65536)
    float* z_e  = y + 1048576;                     // (16384,64)
    float* idsf = y + 2097152;                     // (16384,)

    // workspace overlay: A = 16.7M floats (67MB), Bf = 8.4M floats (33.6MB)
    float* A  = (float*)d_ws;
    float* Bf = A + 16777216;

    // Scratch in y batches 14-15 (dead until final k_last q=3 overwrites):
    // encW: 81920 floats; Afrag: 81920 ushorts (40960 floats).
    float*  encW  = y + 14 * 65536;
    ushort* Afrag = (ushort*)(encW + 81920);

    k_prepack_enc<<<dim3(320), 256, 0, stream>>>(enc_w, encW);
    k_prepack<<<dim3(320), 256, 0, stream>>>(dec_w, Afrag);

    // encoder (fp32, LDS-staged, conflict-free reads, VGPR weights)
    k_enc01<<<dim3(128, 16), 256, 0, stream>>>(x, enc_w0, enc_b, encW, enc_b + 64, A);
    k_enc_conv<<<dim3(64, 16), 256, 0, stream>>>(A,  encW + 1 * 16384, enc_b + 2 * 64, Bf, 16384, 8192, 0);
    k_enc_conv<<<dim3(32, 16), 256, 0, stream>>>(Bf, encW + 2 * 16384, enc_b + 3 * 64, A,  8192,  4096, 0);
    k_enc_conv<<<dim3(16, 16), 256, 0, stream>>>(A,  encW + 3 * 16384, enc_b + 4 * 64, Bf, 4096,  2048, 0);
    k_enc_conv<<<dim3(8, 16),  256, 0, stream>>>(Bf, encW + 4 * 16384, enc_b + 5 * 64, z_e, 2048, 1024, 1);
    // vector quantize -> g in A
    k_vq<<<256, 512, 0, stream>>>(z_e, cb, idsf, A);

    // decoder (bf16 MFMA)
    k_dec_mfma<<<dim3(16, 16),  256, 0, stream>>>(A,  Afrag + 0 * 16384, dec_b + 0 * 64, Bf, 1024);
    k_dec_mfma<<<dim3(32, 16),  256, 0, stream>>>(Bf, Afrag + 1 * 16384, dec_b + 1 * 64, A,  2048);
    k_dec_mfma<<<dim3(64, 16),  256, 0, stream>>>(A,  Afrag + 2 * 16384, dec_b + 2 * 64, Bf, 4096);
    k_dec_mfma<<<dim3(128, 16), 256, 0, stream>>>(Bf, Afrag + 3 * 16384, dec_b + 3 * 64, A,  8192);
    for (int q = 0; q < 4; ++q) {
        k_dec_mfma<<<dim3(256, 4), 256, 0, stream>>>(A + (size_t)q * 4 * 64 * 16384,
                                                     Afrag + 4 * 16384, dec_b + 4 * 64, Bf, 16384);
        k_last<<<dim3(128, 4), 256, 0, stream>>>(Bf, dec_wl, dec_bl, y, q * 4);
    }
}

// Round 9
// 574.725 us; speedup vs baseline: 1.2458x; 1.1245x over previous
//
#include <hip/hip_runtime.h>

#define CH 64
#define TILE 128

typedef short s16x8 __attribute__((ext_vector_type(8)));
typedef float f32x4 __attribute__((ext_vector_type(4)));

static __device__ __forceinline__ ushort f2bf(float f) {
    union { float f; uint u; } v; v.f = f;
    const uint r = (v.u + 0x7FFFu + ((v.u >> 16) & 1u)) >> 16;
    return (ushort)r;
}
static __device__ __forceinline__ float bf2f(ushort u) {
    union { uint u; float f; } v; v.u = ((uint)u) << 16; return v.f;
}

// =====================================================================
// Prepack encoder weights (5,64,64,4) [o][i][tau] -> [L][i][o][tau]
// =====================================================================
__global__ __launch_bounds__(256) void k_prepack_enc(
    const float* __restrict__ enc_w, float* __restrict__ encW)
{
    const int idx = blockIdx.x * 256 + threadIdx.x;   // 81920
    const int tau = idx & 3;
    const int o = (idx >> 2) & 63;
    const int i = (idx >> 8) & 63;
    const int L = idx >> 14;
    encW[idx] = enc_w[(((size_t)L * 64 + o) * 64 + i) * 4 + tau];
}

// =====================================================================
// ENCODER (fp32) — unchanged from round 7
// =====================================================================
__device__ __forceinline__ void stage_half(
    const float* __restrict__ inb, float (*inT)[264], int half,
    int m0, int Lin, int tid)
{
    const int r = tid >> 3;
    const int i = half * 32 + r;
    const int seg = tid & 7;
    const float* src = inb + (size_t)i * Lin + 2 * m0 + 32 * seg;
    float* dst = inT[r] + 1 + 32 * seg;
#pragma unroll
    for (int t = 0; t < 8; ++t) {
        const float4 v = *(const float4*)(src + 4 * t);
        float* d = dst + 4 * t;
        d[0] = v.x;
        *(float2*)(d + 1) = make_float2(v.y, v.z);
        d[3] = v.w;
    }
    if (tid < 64) {
        const int rr = tid & 31, side = tid >> 5;
        const int pl = side ? 257 : 0;
        const int p = 2 * m0 - 1 + pl;
        inT[rr][pl] = (p >= 0 && p < Lin) ? inb[(size_t)(half * 32 + rr) * Lin + p] : 0.f;
    }
}

__device__ __forceinline__ void conv_accum_half(
    const float (*inT)[264], const float* __restrict__ wpk, int ibase,
    float acc[4][8], int og, int pg)
{
    const float* wI = wpk + og * 16 + (size_t)ibase * 256;
    for (int ii = 0; ii < 32; ++ii) {
        const float* wp = wI + ii * 256;
        const float4 w0 = *(const float4*)(wp + 0);
        const float4 w1 = *(const float4*)(wp + 4);
        const float4 w2 = *(const float4*)(wp + 8);
        const float4 w3 = *(const float4*)(wp + 12);
        const float* row = inT[ii];
#pragma unroll
        for (int j = 0; j < 4; ++j) {
            const int base = 4 * pg + 64 * j;
            const float2 xa = *(const float2*)(row + base);
            const float2 xb = *(const float2*)(row + base + 2);
            const float2 xc = *(const float2*)(row + base + 4);
            acc[0][2*j]   += w0.x * xa.x + w0.y * xa.y + w0.z * xb.x + w0.w * xb.y;
            acc[1][2*j]   += w1.x * xa.x + w1.y * xa.y + w1.z * xb.x + w1.w * xb.y;
            acc[2][2*j]   += w2.x * xa.x + w2.y * xa.y + w2.z * xb.x + w2.w * xb.y;
            acc[3][2*j]   += w3.x * xa.x + w3.y * xa.y + w3.z * xb.x + w3.w * xb.y;
            acc[0][2*j+1] += w0.x * xb.x + w0.y * xb.y + w0.z * xc.x + w0.w * xc.y;
            acc[1][2*j+1] += w1.x * xb.x + w1.y * xb.y + w1.z * xc.x + w1.w * xc.y;
            acc[2][2*j+1] += w2.x * xb.x + w2.y * xb.y + w2.z * xc.x + w2.w * xc.y;
            acc[3][2*j+1] += w3.x * xb.x + w3.y * xb.y + w3.z * xc.x + w3.w * xc.y;
        }
    }
}

__device__ __forceinline__ void conv_epilogue(
    float acc[4][8], float* __restrict__ out,
    int b, int m0, int Lout, int transpose, int og, int pg)
{
    if (!transpose) {
#pragma unroll
        for (int oo = 0; oo < 4; ++oo) {
            float* ob = out + ((size_t)b * CH + og * 4 + oo) * Lout + m0 + 2 * pg;
#pragma unroll
            for (int j = 0; j < 4; ++j) {
                float2 v;
                v.x = fmaxf(acc[oo][2*j], 0.f);
                v.y = fmaxf(acc[oo][2*j+1], 0.f);
                *(float2*)(ob + 32 * j) = v;
            }
        }
    } else {
#pragma unroll
        for (int j = 0; j < 4; ++j)
#pragma unroll
            for (int h = 0; h < 2; ++h) {
                const int ml = 2 * pg + 32 * j + h;
                float* ob = out + ((size_t)b * Lout + m0 + ml) * CH + og * 4;
                float4 v;
                v.x = fmaxf(acc[0][2*j+h], 0.f);
                v.y = fmaxf(acc[1][2*j+h], 0.f);
                v.z = fmaxf(acc[2][2*j+h], 0.f);
                v.w = fmaxf(acc[3][2*j+h], 0.f);
                *(float4*)ob = v;
            }
    }
}

__global__ __launch_bounds__(256) void k_enc_conv(
    const float* __restrict__ in, const float* __restrict__ wpk,
    const float* __restrict__ bias, float* __restrict__ out,
    int Lin, int Lout, int transpose)
{
    __shared__ float inT[32][264];
    const int m0 = blockIdx.x * TILE;
    const int b = blockIdx.y;
    const int tid = threadIdx.x;
    const int og = tid >> 4, pg = tid & 15;
    const float* inb = in + (size_t)b * CH * Lin;
    float acc[4][8];
#pragma unroll
    for (int oo = 0; oo < 4; ++oo) {
        const float bv = bias[og * 4 + oo];
#pragma unroll
        for (int j = 0; j < 8; ++j) acc[oo][j] = bv;
    }
    stage_half(inb, inT, 0, m0, Lin, tid);
    __syncthreads();
    conv_accum_half(inT, wpk, 0, acc, og, pg);
    __syncthreads();
    stage_half(inb, inT, 1, m0, Lin, tid);
    __syncthreads();
    conv_accum_half(inT, wpk, 32, acc, og, pg);
    conv_epilogue(acc, out, b, m0, Lout, transpose, og, pg);
}

__global__ __launch_bounds__(256) void k_enc01(
    const float* __restrict__ x, const float* __restrict__ w0,
    const float* __restrict__ b0, const float* __restrict__ wpk0,
    const float* __restrict__ b1, float* __restrict__ out)
{
    __shared__ float xl[520];
    __shared__ float e0s[32][264];
    const int m0 = blockIdx.x * TILE;
    const int b = blockIdx.y;
    const int tid = threadIdx.x;
    const int og = tid >> 4, pg = tid & 15;
    const float* xb = x + (size_t)b * 65536;
    const int x0i = 4 * m0 - 3;
    for (int xi = tid; xi < 518; xi += 256) {
        const int q = x0i + xi;
        xl[xi] = (q >= 0 && q < 65536) ? xb[q] : 0.f;
    }
    float acc[4][8];
#pragma unroll
    for (int oo = 0; oo < 4; ++oo) {
        const float bv = b1[og * 4 + oo];
#pragma unroll
        for (int j = 0; j < 8; ++j) acc[oo][j] = bv;
    }
    const int r = tid >> 3;
    const int oct = tid & 7;
    const int pbase = 2 * m0 - 1;
    __syncthreads();
    for (int half = 0; half < 2; ++half) {
        {
            const int i = half * 32 + r;
            const float4 wv = *(const float4*)(w0 + i * 4);
            const float bv = b0[i];
            for (int t = 0; t < 33; ++t) {
                const int pl = oct * 33 + t;
                if (pl < 258) {
                    const int pe = pbase + pl;
                    const float* xp = xl + 2 * pl;
                    const float v = wv.x * xp[0] + wv.y * xp[1] + wv.z * xp[2] + wv.w * xp[3] + bv;
                    e0s[r][pl] = (pe >= 0 && pe < 32768) ? fmaxf(v, 0.f) : 0.f;
                }
            }
        }
        __syncthreads();
        conv_accum_half(e0s, wpk0, half * 32, acc, og, pg);
        __syncthreads();
    }
    conv_epilogue(acc, out, b, m0, 16384, 0, og, pg);
}

// =====================================================================
// VQ — unchanged
// =====================================================================
__global__ __launch_bounds__(512) void k_vq(
    const float* __restrict__ z, const float* __restrict__ cb,
    float* __restrict__ idsf, float* __restrict__ g)
{
    __shared__ float c2s[1024];
    __shared__ float rval[8][64];
    __shared__ int   ridx[8][64];
    __shared__ int   widx[64];
    const int t0 = blockIdx.x * 64;
    const int tid = threadIdx.x;
    const int lane = tid & 63;
    const int wv = __builtin_amdgcn_readfirstlane(tid >> 6);

    for (int c = tid; c < 1024; c += 512) {
        const float* cp = cb + (size_t)c * 64;
        float s0 = 0.f, s1 = 0.f, s2 = 0.f, s3 = 0.f;
#pragma unroll
        for (int d = 0; d < 64; d += 4) {
            const float4 v = *(const float4*)(cp + d);
            s0 += v.x * v.x; s1 += v.y * v.y; s2 += v.z * v.z; s3 += v.w * v.w;
        }
        c2s[c] = (s0 + s1) + (s2 + s3);
    }
    float pz[64];
    {
        const float* zp = z + (size_t)(t0 + lane) * 64;
#pragma unroll
        for (int d = 0; d < 64; d += 4) {
            const float4 v = *(const float4*)(zp + d);
            pz[d] = -2.f * v.x; pz[d + 1] = -2.f * v.y;
            pz[d + 2] = -2.f * v.z; pz[d + 3] = -2.f * v.w;
        }
    }
    __syncthreads();
    float best = 3.0e38f; int bidx = 0;
    const int cbase = wv * 128;
    for (int cc = 0; cc < 128; ++cc) {
        const int code = cbase + cc;
        const float* cp = cb + (size_t)code * 64;   // uniform -> s_load
        float a0 = 0.f, a1 = 0.f, a2 = 0.f, a3 = 0.f;
#pragma unroll
        for (int d = 0; d < 64; d += 4) {
            a0 += cp[d] * pz[d];
            a1 += cp[d + 1] * pz[d + 1];
            a2 += cp[d + 2] * pz[d + 2];
            a3 += cp[d + 3] * pz[d + 3];
        }
        const float dist = c2s[code] + ((a0 + a1) + (a2 + a3));
        if (dist < best) { best = dist; bidx = code; }
    }
    rval[wv][lane] = best; ridx[wv][lane] = bidx;
    __syncthreads();
    if (tid < 64) {
        float bv = rval[0][tid]; int bi = ridx[0][tid];
#pragma unroll
        for (int k2 = 1; k2 < 8; ++k2) {
            const float v = rval[k2][tid];
            if (v < bv) { bv = v; bi = ridx[k2][tid]; }
        }
        widx[tid] = bi;
        idsf[t0 + tid] = (float)bi;
    }
    __syncthreads();
    const int bb = t0 >> 10;
    const int mb = t0 & 1023;
    for (int e = tid; e < 4096; e += 512) {
        const int tok = e & 63;
        const int d = e >> 6;
        g[((size_t)bb * CH + d) * 1024 + mb + tok] = cb[(size_t)widx[tok] * 64 + d];
    }
}

// =====================================================================
// DECODER v2: per-tap K=64 GEMMs, single X staging (bf16 [u][i], stride 72).
// d4/y relations: d4[o][2u]=b+Σ w1·X[u]+w3·X[u-1]; d4[o][2u+1]=b+Σ w2·X[u]+w0·X[u+1]
// Afrag layout [L][tap][m][kt][lane][j]: o=m*16+(lane&15), i=kt*32+(lane>>4)*8+j
// =====================================================================
__global__ __launch_bounds__(256) void k_prepack(
    const float* __restrict__ dec_w, ushort* __restrict__ Afrag)
{
    const int idx = blockIdx.x * 256 + threadIdx.x;   // 81920
    const int j    = idx & 7;
    const int lane = (idx >> 3) & 63;
    const int kt   = (idx >> 9) & 1;
    const int m    = (idx >> 10) & 3;
    const int tap  = (idx >> 12) & 3;
    const int L    = idx >> 14;
    const int o = m * 16 + (lane & 15);
    const int i = kt * 32 + ((lane >> 4) << 3) + j;
    Afrag[idx] = f2bf(dec_w[(((size_t)L * 64 + i) * 64 + o) * 4 + tap]);
}

// stage X[b-row][u0-2 .. u0+65] -> Xs[row = u-u0+2][i] bf16, row stride 72
__device__ __forceinline__ void stage_X(
    const float* __restrict__ Xb, ushort* __restrict__ Xs, int u0, int Lin, int tid)
{
    for (int e = tid; e < 1088; e += 256) {
        const int i = e & 63;
        const int u4 = e >> 6;            // 0..16
        const int bu = u0 - 2 + 4 * u4;
        const float* src = Xb + (size_t)i * Lin;
        float v[4];
        if (bu >= 0 && bu + 3 < Lin) {
            const float2 p0 = *(const float2*)(src + bu);
            const float2 p1 = *(const float2*)(src + bu + 2);
            v[0] = p0.x; v[1] = p0.y; v[2] = p1.x; v[3] = p1.y;
        } else {
#pragma unroll
            for (int d = 0; d < 4; ++d) {
                const int u = bu + d;
                v[d] = (u >= 0 && u < Lin) ? src[u] : 0.f;
            }
        }
        ushort* dst = Xs + (size_t)(4 * u4) * 72 + i;
#pragma unroll
        for (int d = 0; d < 4; ++d) dst[(size_t)d * 72] = f2bf(v[d]);
    }
}

// compute the 8 accumulators for this thread (m index -> accE[m], accO[m])
__device__ __forceinline__ void dec_mfma_compute(
    const ushort* __restrict__ Xs, const ushort* __restrict__ AfragL,
    int tid, f32x4 accE[4], f32x4 accO[4], int& ul_out, int& kg_out, int& lane_out)
{
    const int lane = tid & 63;
    const int wave = tid >> 6;
    const int col = lane & 15, kg = lane >> 4;
    const int ul = wave * 16 + col;
    const ushort* basep = Xs + kg * 8;
    s16x8 Bm1[2], B0[2], Bp1[2];
#pragma unroll
    for (int kt = 0; kt < 2; ++kt) {
        Bm1[kt] = *(const s16x8*)(basep + (ul + 1) * 72 + kt * 32);
        B0[kt]  = *(const s16x8*)(basep + (ul + 2) * 72 + kt * 32);
        Bp1[kt] = *(const s16x8*)(basep + (ul + 3) * 72 + kt * 32);
    }
    const s16x8* Af = (const s16x8*)AfragL;
#pragma unroll
    for (int m = 0; m < 4; ++m) {
        f32x4 aE = {0.f, 0.f, 0.f, 0.f};
        f32x4 aO = {0.f, 0.f, 0.f, 0.f};
#pragma unroll
        for (int kt = 0; kt < 2; ++kt) {
            aE = __builtin_amdgcn_mfma_f32_16x16x32_bf16(
                Af[((1 * 4 + m) * 2 + kt) * 64 + lane], B0[kt], aE, 0, 0, 0);
            aE = __builtin_amdgcn_mfma_f32_16x16x32_bf16(
                Af[((3 * 4 + m) * 2 + kt) * 64 + lane], Bm1[kt], aE, 0, 0, 0);
            aO = __builtin_amdgcn_mfma_f32_16x16x32_bf16(
                Af[((2 * 4 + m) * 2 + kt) * 64 + lane], B0[kt], aO, 0, 0, 0);
            aO = __builtin_amdgcn_mfma_f32_16x16x32_bf16(
                Af[((0 * 4 + m) * 2 + kt) * 64 + lane], Bp1[kt], aO, 0, 0, 0);
        }
        accE[m] = aE;
        accO[m] = aO;
    }
    ul_out = ul; kg_out = kg; lane_out = lane;
}

// generic convT layer (output fp32 to ws)
__global__ __launch_bounds__(256) void k_dec2(
    const float* __restrict__ X, const ushort* __restrict__ AfragL,
    const float* __restrict__ bias, float* __restrict__ Y, int Lin)
{
    __shared__ ushort Xs[68 * 72];
    const int u0 = blockIdx.x * 64;
    const int b  = blockIdx.y;
    const int tid = threadIdx.x;
    const int Lout = Lin * 2;
    stage_X(X + (size_t)b * CH * Lin, Xs, u0, Lin, tid);
    __syncthreads();
    f32x4 accE[4], accO[4];
    int ul, kg, lane;
    dec_mfma_compute(Xs, AfragL, tid, accE, accO, ul, kg, lane);
    const int n2 = 2 * (u0 + ul);
#pragma unroll
    for (int m = 0; m < 4; ++m) {
        const float4 bm4 = *(const float4*)(bias + m * 16 + kg * 4);
        const float bb[4] = {bm4.x, bm4.y, bm4.z, bm4.w};
        float* yo = Y + ((size_t)b * CH + m * 16 + kg * 4) * Lout + n2;
#pragma unroll
        for (int r = 0; r < 4; ++r) {
            float2 v;
            v.x = fmaxf(accE[m][r] + bb[r], 0.f);
            v.y = fmaxf(accO[m][r] + bb[r], 0.f);
            *(float2*)(yo + (size_t)r * Lout) = v;
        }
    }
}

// fused dec4 + last convT: d4 tile in LDS (+2 halo cols), y written directly
__global__ __launch_bounds__(256) void k_dec4y(
    const float* __restrict__ X, const ushort* __restrict__ AfragL,
    const float* __restrict__ w4, const float* __restrict__ bias,
    const float* __restrict__ wl, const float* __restrict__ blp,
    float* __restrict__ y)
{
    __shared__ ushort Xs[68 * 72];
    __shared__ float d4s[64][130];   // col vl = v - (2u0-1); 0,129 = halo
    const int u0 = blockIdx.x * 64;
    const int b  = blockIdx.y;
    const int tid = threadIdx.x;
    const int Lin = 16384;
    stage_X(X + (size_t)b * CH * Lin, Xs, u0, Lin, tid);
    __syncthreads();
    f32x4 accE[4], accO[4];
    int ul, kg, lane;
    dec_mfma_compute(Xs, AfragL, tid, accE, accO, ul, kg, lane);
#pragma unroll
    for (int m = 0; m < 4; ++m) {
        const float4 bm4 = *(const float4*)(bias + m * 16 + kg * 4);
        const float bb[4] = {bm4.x, bm4.y, bm4.z, bm4.w};
#pragma unroll
        for (int r = 0; r < 4; ++r) {
            const int o = m * 16 + kg * 4 + r;
            d4s[o][2 * ul + 1] = fmaxf(accE[m][r] + bb[r], 0.f);
            d4s[o][2 * ul + 2] = fmaxf(accO[m][r] + bb[r], 0.f);
        }
    }
    // halo cols: vl=0 -> v=2u0-1 (odd, u=u0-1); vl=129 -> v=2u0+128 (even, u=u0+64)
    if (tid < 128) {
        const int side = tid >> 6;
        const int o = tid & 63;
        float acc = bias[o];
        if (side == 0) {
            for (int i = 0; i < 64; ++i) {
                const float xu = bf2f(Xs[1 * 72 + i]);   // X[u0-1]
                const float xp = bf2f(Xs[2 * 72 + i]);   // X[u0]
                const float* wp = w4 + ((size_t)i * 64 + o) * 4;
                acc += wp[2] * xu + wp[0] * xp;
            }
            d4s[o][0] = (u0 > 0) ? fmaxf(acc, 0.f) : 0.f;
        } else {
            for (int i = 0; i < 64; ++i) {
                const float xu = bf2f(Xs[66 * 72 + i]);  // X[u0+64]
                const float xm = bf2f(Xs[65 * 72 + i]);  // X[u0+63]
                const float* wp = w4 + ((size_t)i * 64 + o) * 4;
                acc += wp[1] * xu + wp[3] * xm;
            }
            d4s[o][129] = (u0 + 64 < 16384) ? fmaxf(acc, 0.f) : 0.f;
        }
    }
    __syncthreads();
    // y: n = 4*u0 + tid; v=n>>1 -> vl=(tid>>1)+1 in [1,128]
    {
        const int odd = tid & 1;
        const int vl = (tid >> 1) + 1;
        float acc = blp[0];
        for (int o = 0; o < 64; ++o) {
            const float4 wv = *(const float4*)(wl + o * 4);   // uniform -> s_load
            const float xv = d4s[o][vl];
            const float xn = d4s[o][odd ? vl + 1 : vl - 1];
            acc += odd ? (wv.z * xv + wv.x * xn) : (wv.y * xv + wv.w * xn);
        }
        y[(size_t)b * 65536 + 4 * u0 + tid] = acc;
    }
}

extern "C" void kernel_launch(void* const* d_in, const int* in_sizes, int n_in,
                              void* d_out, int out_size, void* d_ws, size_t ws_size,
                              hipStream_t stream) {
    const float* x      = (const float*)d_in[0];
    const float* enc_w0 = (const float*)d_in[1];
    const float* enc_w  = (const float*)d_in[2];   // (5,64,64,4)
    const float* enc_b  = (const float*)d_in[3];   // (6,64)
    const float* cb     = (const float*)d_in[4];   // (1024,64)
    const float* dec_w  = (const float*)d_in[5];   // (5,64,64,4) [in][out][k]
    const float* dec_wl = (const float*)d_in[6];   // (64,1,4)
    const float* dec_b  = (const float*)d_in[7];   // (5,64)
    const float* dec_bl = (const float*)d_in[8];   // (1,)
    float* y    = (float*)d_out;                   // (16,1,65536)
    float* z_e  = y + 1048576;                     // (16384,64)
    float* idsf = y + 2097152;                     // (16384,)

    // workspace overlay: A = 16.7M floats (67MB), Bf = 8.4M floats (33.6MB)
    float* A  = (float*)d_ws;
    float* Bf = A + 16777216;

    // Scratch in y batches 14-15: encW dead after encoder; Afrag (dec) used by
    // k_dec2 L0-L3 from here, then layer-4 slice is d2d-copied into Bf (free
    // after L3) BEFORE k_dec4y overwrites all of y.
    float*  encW  = y + 14 * 65536;
    ushort* Afrag = (ushort*)(encW + 81920);

    k_prepack_enc<<<dim3(320), 256, 0, stream>>>(enc_w, encW);
    k_prepack<<<dim3(320), 256, 0, stream>>>(dec_w, Afrag);

    // encoder (fp32)
    k_enc01<<<dim3(128, 16), 256, 0, stream>>>(x, enc_w0, enc_b, encW, enc_b + 64, A);
    k_enc_conv<<<dim3(64, 16), 256, 0, stream>>>(A,  encW + 1 * 16384, enc_b + 2 * 64, Bf, 16384, 8192, 0);
    k_enc_conv<<<dim3(32, 16), 256, 0, stream>>>(Bf, encW + 2 * 16384, enc_b + 3 * 64, A,  8192,  4096, 0);
    k_enc_conv<<<dim3(16, 16), 256, 0, stream>>>(A,  encW + 3 * 16384, enc_b + 4 * 64, Bf, 4096,  2048, 0);
    k_enc_conv<<<dim3(8, 16),  256, 0, stream>>>(Bf, encW + 4 * 16384, enc_b + 5 * 64, z_e, 2048, 1024, 1);
    // vector quantize -> g in A
    k_vq<<<256, 512, 0, stream>>>(z_e, cb, idsf, A);

    // decoder (bf16 MFMA v2)
    k_dec2<<<dim3(16, 16),  256, 0, stream>>>(A,  Afrag + 0 * 16384, dec_b + 0 * 64, Bf, 1024);
    k_dec2<<<dim3(32, 16),  256, 0, stream>>>(Bf, Afrag + 1 * 16384, dec_b + 1 * 64, A,  2048);
    k_dec2<<<dim3(64, 16),  256, 0, stream>>>(A,  Afrag + 2 * 16384, dec_b + 2 * 64, Bf, 4096);
    k_dec2<<<dim3(128, 16), 256, 0, stream>>>(Bf, Afrag + 3 * 16384, dec_b + 3 * 64, A,  8192);
    // move layer-4 A-frags out of y (k_dec4y overwrites all of y)
    (void)hipMemcpyAsync(Bf, Afrag + 4 * 16384, 16384 * sizeof(ushort),
                         hipMemcpyDeviceToDevice, stream);
    k_dec4y<<<dim3(256, 16), 256, 0, stream>>>(A, (const ushort*)Bf,
                                               dec_w + 4 * 16384, dec_b + 4 * 64,
                                               dec_wl, dec_bl, y);
}

// Round 10
// 542.618 us; speedup vs baseline: 1.3195x; 1.0592x over previous
//
#include <hip/hip_runtime.h>

#define CH 64
#define TILE 128

typedef short s16x8 __attribute__((ext_vector_type(8)));
typedef float f32x4 __attribute__((ext_vector_type(4)));

static __device__ __forceinline__ ushort f2bf(float f) {
    union { float f; uint u; } v; v.f = f;
    const uint r = (v.u + 0x7FFFu + ((v.u >> 16) & 1u)) >> 16;
    return (ushort)r;
}
static __device__ __forceinline__ float bf2f(ushort u) {
    union { uint u; float f; } v; v.u = ((uint)u) << 16; return v.f;
}

// =====================================================================
// Prepack encoder weights (5,64,64,4) [o][i][tau] -> [L][i][o][tau]
// =====================================================================
__global__ __launch_bounds__(256) void k_prepack_enc(
    const float* __restrict__ enc_w, float* __restrict__ encW)
{
    const int idx = blockIdx.x * 256 + threadIdx.x;   // 81920
    const int tau = idx & 3;
    const int o = (idx >> 2) & 63;
    const int i = (idx >> 8) & 63;
    const int L = idx >> 14;
    encW[idx] = enc_w[(((size_t)L * 64 + o) * 64 + i) * 4 + tau];
}

// =====================================================================
// ENCODER (fp32) — unchanged
// =====================================================================
__device__ __forceinline__ void stage_half(
    const float* __restrict__ inb, float (*inT)[264], int half,
    int m0, int Lin, int tid)
{
    const int r = tid >> 3;
    const int i = half * 32 + r;
    const int seg = tid & 7;
    const float* src = inb + (size_t)i * Lin + 2 * m0 + 32 * seg;
    float* dst = inT[r] + 1 + 32 * seg;
#pragma unroll
    for (int t = 0; t < 8; ++t) {
        const float4 v = *(const float4*)(src + 4 * t);
        float* d = dst + 4 * t;
        d[0] = v.x;
        *(float2*)(d + 1) = make_float2(v.y, v.z);
        d[3] = v.w;
    }
    if (tid < 64) {
        const int rr = tid & 31, side = tid >> 5;
        const int pl = side ? 257 : 0;
        const int p = 2 * m0 - 1 + pl;
        inT[rr][pl] = (p >= 0 && p < Lin) ? inb[(size_t)(half * 32 + rr) * Lin + p] : 0.f;
    }
}

__device__ __forceinline__ void conv_accum_half(
    const float (*inT)[264], const float* __restrict__ wpk, int ibase,
    float acc[4][8], int og, int pg)
{
    const float* wI = wpk + og * 16 + (size_t)ibase * 256;
    for (int ii = 0; ii < 32; ++ii) {
        const float* wp = wI + ii * 256;
        const float4 w0 = *(const float4*)(wp + 0);
        const float4 w1 = *(const float4*)(wp + 4);
        const float4 w2 = *(const float4*)(wp + 8);
        const float4 w3 = *(const float4*)(wp + 12);
        const float* row = inT[ii];
#pragma unroll
        for (int j = 0; j < 4; ++j) {
            const int base = 4 * pg + 64 * j;
            const float2 xa = *(const float2*)(row + base);
            const float2 xb = *(const float2*)(row + base + 2);
            const float2 xc = *(const float2*)(row + base + 4);
            acc[0][2*j]   += w0.x * xa.x + w0.y * xa.y + w0.z * xb.x + w0.w * xb.y;
            acc[1][2*j]   += w1.x * xa.x + w1.y * xa.y + w1.z * xb.x + w1.w * xb.y;
            acc[2][2*j]   += w2.x * xa.x + w2.y * xa.y + w2.z * xb.x + w2.w * xb.y;
            acc[3][2*j]   += w3.x * xa.x + w3.y * xa.y + w3.z * xb.x + w3.w * xb.y;
            acc[0][2*j+1] += w0.x * xb.x + w0.y * xb.y + w0.z * xc.x + w0.w * xc.y;
            acc[1][2*j+1] += w1.x * xb.x + w1.y * xb.y + w1.z * xc.x + w1.w * xc.y;
            acc[2][2*j+1] += w2.x * xb.x + w2.y * xb.y + w2.z * xc.x + w2.w * xc.y;
            acc[3][2*j+1] += w3.x * xb.x + w3.y * xb.y + w3.z * xc.x + w3.w * xc.y;
        }
    }
}

__device__ __forceinline__ void conv_epilogue(
    float acc[4][8], float* __restrict__ out,
    int b, int m0, int Lout, int transpose, int og, int pg)
{
    if (!transpose) {
#pragma unroll
        for (int oo = 0; oo < 4; ++oo) {
            float* ob = out + ((size_t)b * CH + og * 4 + oo) * Lout + m0 + 2 * pg;
#pragma unroll
            for (int j = 0; j < 4; ++j) {
                float2 v;
                v.x = fmaxf(acc[oo][2*j], 0.f);
                v.y = fmaxf(acc[oo][2*j+1], 0.f);
                *(float2*)(ob + 32 * j) = v;
            }
        }
    } else {
#pragma unroll
        for (int j = 0; j < 4; ++j)
#pragma unroll
            for (int h = 0; h < 2; ++h) {
                const int ml = 2 * pg + 32 * j + h;
                float* ob = out + ((size_t)b * Lout + m0 + ml) * CH + og * 4;
                float4 v;
                v.x = fmaxf(acc[0][2*j+h], 0.f);
                v.y = fmaxf(acc[1][2*j+h], 0.f);
                v.z = fmaxf(acc[2][2*j+h], 0.f);
                v.w = fmaxf(acc[3][2*j+h], 0.f);
                *(float4*)ob = v;
            }
    }
}

__global__ __launch_bounds__(256) void k_enc_conv(
    const float* __restrict__ in, const float* __restrict__ wpk,
    const float* __restrict__ bias, float* __restrict__ out,
    int Lin, int Lout, int transpose)
{
    __shared__ float inT[32][264];
    const int m0 = blockIdx.x * TILE;
    const int b = blockIdx.y;
    const int tid = threadIdx.x;
    const int og = tid >> 4, pg = tid & 15;
    const float* inb = in + (size_t)b * CH * Lin;
    float acc[4][8];
#pragma unroll
    for (int oo = 0; oo < 4; ++oo) {
        const float bv = bias[og * 4 + oo];
#pragma unroll
        for (int j = 0; j < 8; ++j) acc[oo][j] = bv;
    }
    stage_half(inb, inT, 0, m0, Lin, tid);
    __syncthreads();
    conv_accum_half(inT, wpk, 0, acc, og, pg);
    __syncthreads();
    stage_half(inb, inT, 1, m0, Lin, tid);
    __syncthreads();
    conv_accum_half(inT, wpk, 32, acc, og, pg);
    conv_epilogue(acc, out, b, m0, Lout, transpose, og, pg);
}

__global__ __launch_bounds__(256) void k_enc01(
    const float* __restrict__ x, const float* __restrict__ w0,
    const float* __restrict__ b0, const float* __restrict__ wpk0,
    const float* __restrict__ b1, float* __restrict__ out)
{
    __shared__ float xl[520];
    __shared__ float e0s[32][264];
    const int m0 = blockIdx.x * TILE;
    const int b = blockIdx.y;
    const int tid = threadIdx.x;
    const int og = tid >> 4, pg = tid & 15;
    const float* xb = x + (size_t)b * 65536;
    const int x0i = 4 * m0 - 3;
    for (int xi = tid; xi < 518; xi += 256) {
        const int q = x0i + xi;
        xl[xi] = (q >= 0 && q < 65536) ? xb[q] : 0.f;
    }
    float acc[4][8];
#pragma unroll
    for (int oo = 0; oo < 4; ++oo) {
        const float bv = b1[og * 4 + oo];
#pragma unroll
        for (int j = 0; j < 8; ++j) acc[oo][j] = bv;
    }
    const int r = tid >> 3;
    const int oct = tid & 7;
    const int pbase = 2 * m0 - 1;
    __syncthreads();
    for (int half = 0; half < 2; ++half) {
        {
            const int i = half * 32 + r;
            const float4 wv = *(const float4*)(w0 + i * 4);
            const float bv = b0[i];
            for (int t = 0; t < 33; ++t) {
                const int pl = oct * 33 + t;
                if (pl < 258) {
                    const int pe = pbase + pl;
                    const float* xp = xl + 2 * pl;
                    const float v = wv.x * xp[0] + wv.y * xp[1] + wv.z * xp[2] + wv.w * xp[3] + bv;
                    e0s[r][pl] = (pe >= 0 && pe < 32768) ? fmaxf(v, 0.f) : 0.f;
                }
            }
        }
        __syncthreads();
        conv_accum_half(e0s, wpk0, half * 32, acc, og, pg);
        __syncthreads();
    }
    conv_epilogue(acc, out, b, m0, 16384, 0, og, pg);
}

// =====================================================================
// VQ — unchanged
// =====================================================================
__global__ __launch_bounds__(512) void k_vq(
    const float* __restrict__ z, const float* __restrict__ cb,
    float* __restrict__ idsf, float* __restrict__ g)
{
    __shared__ float c2s[1024];
    __shared__ float rval[8][64];
    __shared__ int   ridx[8][64];
    __shared__ int   widx[64];
    const int t0 = blockIdx.x * 64;
    const int tid = threadIdx.x;
    const int lane = tid & 63;
    const int wv = __builtin_amdgcn_readfirstlane(tid >> 6);

    for (int c = tid; c < 1024; c += 512) {
        const float* cp = cb + (size_t)c * 64;
        float s0 = 0.f, s1 = 0.f, s2 = 0.f, s3 = 0.f;
#pragma unroll
        for (int d = 0; d < 64; d += 4) {
            const float4 v = *(const float4*)(cp + d);
            s0 += v.x * v.x; s1 += v.y * v.y; s2 += v.z * v.z; s3 += v.w * v.w;
        }
        c2s[c] = (s0 + s1) + (s2 + s3);
    }
    float pz[64];
    {
        const float* zp = z + (size_t)(t0 + lane) * 64;
#pragma unroll
        for (int d = 0; d < 64; d += 4) {
            const float4 v = *(const float4*)(zp + d);
            pz[d] = -2.f * v.x; pz[d + 1] = -2.f * v.y;
            pz[d + 2] = -2.f * v.z; pz[d + 3] = -2.f * v.w;
        }
    }
    __syncthreads();
    float best = 3.0e38f; int bidx = 0;
    const int cbase = wv * 128;
    for (int cc = 0; cc < 128; ++cc) {
        const int code = cbase + cc;
        const float* cp = cb + (size_t)code * 64;   // uniform -> s_load
        float a0 = 0.f, a1 = 0.f, a2 = 0.f, a3 = 0.f;
#pragma unroll
        for (int d = 0; d < 64; d += 4) {
            a0 += cp[d] * pz[d];
            a1 += cp[d + 1] * pz[d + 1];
            a2 += cp[d + 2] * pz[d + 2];
            a3 += cp[d + 3] * pz[d + 3];
        }
        const float dist = c2s[code] + ((a0 + a1) + (a2 + a3));
        if (dist < best) { best = dist; bidx = code; }
    }
    rval[wv][lane] = best; ridx[wv][lane] = bidx;
    __syncthreads();
    if (tid < 64) {
        float bv = rval[0][tid]; int bi = ridx[0][tid];
#pragma unroll
        for (int k2 = 1; k2 < 8; ++k2) {
            const float v = rval[k2][tid];
            if (v < bv) { bv = v; bi = ridx[k2][tid]; }
        }
        widx[tid] = bi;
        idsf[t0 + tid] = (float)bi;
    }
    __syncthreads();
    const int bb = t0 >> 10;
    const int mb = t0 & 1023;
    for (int e = tid; e < 4096; e += 512) {
        const int tok = e & 63;
        const int d = e >> 6;
        g[((size_t)bb * CH + d) * 1024 + mb + tok] = cb[(size_t)widx[tok] * 64 + d];
    }
}

// =====================================================================
// DECODER v2.1: per-tap K=64 GEMMs; stage_X now 4x4 transpose-pack
// (4 global dwordx4 -> 4 ds_write_b64), halo parallelized.
// =====================================================================
__global__ __launch_bounds__(256) void k_prepack(
    const float* __restrict__ dec_w, ushort* __restrict__ Afrag)
{
    const int idx = blockIdx.x * 256 + threadIdx.x;   // 81920
    const int j    = idx & 7;
    const int lane = (idx >> 3) & 63;
    const int kt   = (idx >> 9) & 1;
    const int m    = (idx >> 10) & 3;
    const int tap  = (idx >> 12) & 3;
    const int L    = idx >> 14;
    const int o = m * 16 + (lane & 15);
    const int i = kt * 32 + ((lane >> 4) << 3) + j;
    Afrag[idx] = f2bf(dec_w[(((size_t)L * 64 + i) * 64 + o) * 4 + tap]);
}

// stage X[b-row][u0-2 .. u0+65] -> Xs[row = u-u0+2][i] bf16, row stride 72
// 272 tasks of 4u x 4i: 4 global dwordx4 + 4 packed ds_write_b64
__device__ __forceinline__ void stage_X(
    const float* __restrict__ Xb, ushort* __restrict__ Xs, int u0, int Lin, int tid)
{
    for (int e = tid; e < 272; e += 256) {
        const int i4 = (e & 15) * 4;
        const int u4 = e >> 4;            // 0..16
        const int bu = u0 - 2 + 4 * u4;
        float v[4][4];                    // [di][du]
        if (bu >= 0 && bu + 3 < Lin) {
            const float* src = Xb + (size_t)i4 * Lin + bu;
#pragma unroll
            for (int di = 0; di < 4; ++di) {
                const float4 t = *(const float4*)(src + (size_t)di * Lin);
                v[di][0] = t.x; v[di][1] = t.y; v[di][2] = t.z; v[di][3] = t.w;
            }
        } else {
#pragma unroll
            for (int di = 0; di < 4; ++di)
#pragma unroll
                for (int du = 0; du < 4; ++du) {
                    const int u = bu + du;
                    v[di][du] = (u >= 0 && u < Lin) ? Xb[(size_t)(i4 + di) * Lin + u] : 0.f;
                }
        }
#pragma unroll
        for (int du = 0; du < 4; ++du) {
            ushort4 pk;
            pk.x = f2bf(v[0][du]); pk.y = f2bf(v[1][du]);
            pk.z = f2bf(v[2][du]); pk.w = f2bf(v[3][du]);
            *(ushort4*)(Xs + (size_t)(4 * u4 + du) * 72 + i4) = pk;
        }
    }
}

// compute the 8 accumulators for this thread (m index -> accE[m], accO[m])
__device__ __forceinline__ void dec_mfma_compute(
    const ushort* __restrict__ Xs, const ushort* __restrict__ AfragL,
    int tid, f32x4 accE[4], f32x4 accO[4], int& ul_out, int& kg_out, int& lane_out)
{
    const int lane = tid & 63;
    const int wave = tid >> 6;
    const int col = lane & 15, kg = lane >> 4;
    const int ul = wave * 16 + col;
    const ushort* basep = Xs + kg * 8;
    s16x8 Bm1[2], B0[2], Bp1[2];
#pragma unroll
    for (int kt = 0; kt < 2; ++kt) {
        Bm1[kt] = *(const s16x8*)(basep + (ul + 1) * 72 + kt * 32);
        B0[kt]  = *(const s16x8*)(basep + (ul + 2) * 72 + kt * 32);
        Bp1[kt] = *(const s16x8*)(basep + (ul + 3) * 72 + kt * 32);
    }
    const s16x8* Af = (const s16x8*)AfragL;
#pragma unroll
    for (int m = 0; m < 4; ++m) {
        f32x4 aE = {0.f, 0.f, 0.f, 0.f};
        f32x4 aO = {0.f, 0.f, 0.f, 0.f};
#pragma unroll
        for (int kt = 0; kt < 2; ++kt) {
            aE = __builtin_amdgcn_mfma_f32_16x16x32_bf16(
                Af[((1 * 4 + m) * 2 + kt) * 64 + lane], B0[kt], aE, 0, 0, 0);
            aE = __builtin_amdgcn_mfma_f32_16x16x32_bf16(
                Af[((3 * 4 + m) * 2 + kt) * 64 + lane], Bm1[kt], aE, 0, 0, 0);
            aO = __builtin_amdgcn_mfma_f32_16x16x32_bf16(
                Af[((2 * 4 + m) * 2 + kt) * 64 + lane], B0[kt], aO, 0, 0, 0);
            aO = __builtin_amdgcn_mfma_f32_16x16x32_bf16(
                Af[((0 * 4 + m) * 2 + kt) * 64 + lane], Bp1[kt], aO, 0, 0, 0);
        }
        accE[m] = aE;
        accO[m] = aO;
    }
    ul_out = ul; kg_out = kg; lane_out = lane;
}

// generic convT layer (output fp32 to ws)
__global__ __launch_bounds__(256) void k_dec2(
    const float* __restrict__ X, const ushort* __restrict__ AfragL,
    const float* __restrict__ bias, float* __restrict__ Y, int Lin)
{
    __shared__ ushort Xs[68 * 72];
    const int u0 = blockIdx.x * 64;
    const int b  = blockIdx.y;
    const int tid = threadIdx.x;
    const int Lout = Lin * 2;
    stage_X(X + (size_t)b * CH * Lin, Xs, u0, Lin, tid);
    __syncthreads();
    f32x4 accE[4], accO[4];
    int ul, kg, lane;
    dec_mfma_compute(Xs, AfragL, tid, accE, accO, ul, kg, lane);
    const int n2 = 2 * (u0 + ul);
#pragma unroll
    for (int m = 0; m < 4; ++m) {
        const float4 bm4 = *(const float4*)(bias + m * 16 + kg * 4);
        const float bb[4] = {bm4.x, bm4.y, bm4.z, bm4.w};
        float* yo = Y + ((size_t)b * CH + m * 16 + kg * 4) * Lout + n2;
#pragma unroll
        for (int r = 0; r < 4; ++r) {
            float2 v;
            v.x = fmaxf(accE[m][r] + bb[r], 0.f);
            v.y = fmaxf(accO[m][r] + bb[r], 0.f);
            *(float2*)(yo + (size_t)r * Lout) = v;
        }
    }
}

// fused dec4 + last convT: d4 tile in LDS (+2 halo cols), y written directly
__global__ __launch_bounds__(256) void k_dec4y(
    const float* __restrict__ X, const ushort* __restrict__ AfragL,
    const float* __restrict__ w4, const float* __restrict__ bias,
    const float* __restrict__ wl, const float* __restrict__ blp,
    float* __restrict__ y)
{
    __shared__ ushort Xs[68 * 72];
    __shared__ float d4s[64][130];   // col vl = v - (2u0-1); 0,129 = halo
    const int u0 = blockIdx.x * 64;
    const int b  = blockIdx.y;
    const int tid = threadIdx.x;
    const int Lin = 16384;
    stage_X(X + (size_t)b * CH * Lin, Xs, u0, Lin, tid);
    __syncthreads();
    f32x4 accE[4], accO[4];
    int ul, kg, lane;
    dec_mfma_compute(Xs, AfragL, tid, accE, accO, ul, kg, lane);
#pragma unroll
    for (int m = 0; m < 4; ++m) {
        const float4 bm4 = *(const float4*)(bias + m * 16 + kg * 4);
        const float bb[4] = {bm4.x, bm4.y, bm4.z, bm4.w};
#pragma unroll
        for (int r = 0; r < 4; ++r) {
            const int o = m * 16 + kg * 4 + r;
            d4s[o][2 * ul + 1] = fmaxf(accE[m][r] + bb[r], 0.f);
            d4s[o][2 * ul + 2] = fmaxf(accO[m][r] + bb[r], 0.f);
        }
    }
    // halo cols, parallel over all 256 threads:
    // task = (side, o, half): 32-i partial, combine via shfl_xor(1)
    {
        const int side = tid >> 7;
        const int o = (tid >> 1) & 63;
        const int half = tid & 1;
        const int ib = half * 32;
        float part = 0.f;
        if (side == 0) {
            for (int i = ib; i < ib + 32; ++i) {
                const float xu = bf2f(Xs[1 * 72 + i]);   // X[u0-1]
                const float xp = bf2f(Xs[2 * 72 + i]);   // X[u0]
                const float* wp = w4 + ((size_t)i * 64 + o) * 4;
                part += wp[2] * xu + wp[0] * xp;
            }
        } else {
            for (int i = ib; i < ib + 32; ++i) {
                const float xu = bf2f(Xs[66 * 72 + i]);  // X[u0+64]
                const float xm = bf2f(Xs[65 * 72 + i]);  // X[u0+63]
                const float* wp = w4 + ((size_t)i * 64 + o) * 4;
                part += wp[1] * xu + wp[3] * xm;
            }
        }
        part += __shfl_xor(part, 1);
        if (half == 0) {
            const float acc = bias[o] + part;
            if (side == 0) d4s[o][0]   = (u0 > 0)          ? fmaxf(acc, 0.f) : 0.f;
            else           d4s[o][129] = (u0 + 64 < 16384) ? fmaxf(acc, 0.f) : 0.f;
        }
    }
    __syncthreads();
    // y: n = 4*u0 + tid; v=n>>1 -> vl=(tid>>1)+1 in [1,128]
    {
        const int odd = tid & 1;
        const int vl = (tid >> 1) + 1;
        float acc = blp[0];
        for (int o = 0; o < 64; ++o) {
            const float4 wv = *(const float4*)(wl + o * 4);   // uniform -> s_load
            const float xv = d4s[o][vl];
            const float xn = d4s[o][odd ? vl + 1 : vl - 1];
            acc += odd ? (wv.z * xv + wv.x * xn) : (wv.y * xv + wv.w * xn);
        }
        y[(size_t)b * 65536 + 4 * u0 + tid] = acc;
    }
}

extern "C" void kernel_launch(void* const* d_in, const int* in_sizes, int n_in,
                              void* d_out, int out_size, void* d_ws, size_t ws_size,
                              hipStream_t stream) {
    const float* x      = (const float*)d_in[0];
    const float* enc_w0 = (const float*)d_in[1];
    const float* enc_w  = (const float*)d_in[2];   // (5,64,64,4)
    const float* enc_b  = (const float*)d_in[3];   // (6,64)
    const float* cb     = (const float*)d_in[4];   // (1024,64)
    const float* dec_w  = (const float*)d_in[5];   // (5,64,64,4) [in][out][k]
    const float* dec_wl = (const float*)d_in[6];   // (64,1,4)
    const float* dec_b  = (const float*)d_in[7];   // (5,64)
    const float* dec_bl = (const float*)d_in[8];   // (1,)
    float* y    = (float*)d_out;                   // (16,1,65536)
    float* z_e  = y + 1048576;                     // (16384,64)
    float* idsf = y + 2097152;                     // (16384,)

    // workspace overlay: A = 16.7M floats (67MB), Bf = 8.4M floats (33.6MB)
    float* A  = (float*)d_ws;
    float* Bf = A + 16777216;

    // Scratch in y batches 14-15: encW dead after encoder; Afrag (dec) used by
    // k_dec2 L0-L3 from here, then layer-4 slice is d2d-copied into Bf (free
    // after L3) BEFORE k_dec4y overwrites all of y.
    float*  encW  = y + 14 * 65536;
    ushort* Afrag = (ushort*)(encW + 81920);

    k_prepack_enc<<<dim3(320), 256, 0, stream>>>(enc_w, encW);
    k_prepack<<<dim3(320), 256, 0, stream>>>(dec_w, Afrag);

    // encoder (fp32)
    k_enc01<<<dim3(128, 16), 256, 0, stream>>>(x, enc_w0, enc_b, encW, enc_b + 64, A);
    k_enc_conv<<<dim3(64, 16), 256, 0, stream>>>(A,  encW + 1 * 16384, enc_b + 2 * 64, Bf, 16384, 8192, 0);
    k_enc_conv<<<dim3(32, 16), 256, 0, stream>>>(Bf, encW + 2 * 16384, enc_b + 3 * 64, A,  8192,  4096, 0);
    k_enc_conv<<<dim3(16, 16), 256, 0, stream>>>(A,  encW + 3 * 16384, enc_b + 4 * 64, Bf, 4096,  2048, 0);
    k_enc_conv<<<dim3(8, 16),  256, 0, stream>>>(Bf, encW + 4 * 16384, enc_b + 5 * 64, z_e, 2048, 1024, 1);
    // vector quantize -> g in A
    k_vq<<<256, 512, 0, stream>>>(z_e, cb, idsf, A);

    // decoder (bf16 MFMA v2.1)
    k_dec2<<<dim3(16, 16),  256, 0, stream>>>(A,  Afrag + 0 * 16384, dec_b + 0 * 64, Bf, 1024);
    k_dec2<<<dim3(32, 16),  256, 0, stream>>>(Bf, Afrag + 1 * 16384, dec_b + 1 * 64, A,  2048);
    k_dec2<<<dim3(64, 16),  256, 0, stream>>>(A,  Afrag + 2 * 16384, dec_b + 2 * 64, Bf, 4096);
    k_dec2<<<dim3(128, 16), 256, 0, stream>>>(Bf, Afrag + 3 * 16384, dec_b + 3 * 64, A,  8192);
    // move layer-4 A-frags out of y (k_dec4y overwrites all of y)
    (void)hipMemcpyAsync(Bf, Afrag + 4 * 16384, 16384 * sizeof(ushort),
                         hipMemcpyDeviceToDevice, stream);
    k_dec4y<<<dim3(256, 16), 256, 0, stream>>>(A, (const ushort*)Bf,
                                               dec_w + 4 * 16384, dec_b + 4 * 64,
                                               dec_wl, dec_bl, y);
}

// Round 11
// 533.654 us; speedup vs baseline: 1.3417x; 1.0168x over previous
//
#include <hip/hip_runtime.h>

#define CH 64
#define TILE 128

typedef short s16x8 __attribute__((ext_vector_type(8)));
typedef float f32x4 __attribute__((ext_vector_type(4)));

static __device__ __forceinline__ ushort f2bf(float f) {
    union { float f; uint u; } v; v.f = f;
    const uint r = (v.u + 0x7FFFu + ((v.u >> 16) & 1u)) >> 16;
    return (ushort)r;
}
static __device__ __forceinline__ float bf2f(ushort u) {
    union { uint u; float f; } v; v.u = ((uint)u) << 16; return v.f;
}

// =====================================================================
// Prepack encoder weights (5,64,64,4) [o][i][tau] -> [L][i][o][tau]
// =====================================================================
__global__ __launch_bounds__(256) void k_prepack_enc(
    const float* __restrict__ enc_w, float* __restrict__ encW)
{
    const int idx = blockIdx.x * 256 + threadIdx.x;   // 81920
    const int tau = idx & 3;
    const int o = (idx >> 2) & 63;
    const int i = (idx >> 8) & 63;
    const int L = idx >> 14;
    encW[idx] = enc_w[(((size_t)L * 64 + o) * 64 + i) * 4 + tau];
}

// =====================================================================
// ENCODER (fp32) — unchanged
// =====================================================================
__device__ __forceinline__ void stage_half(
    const float* __restrict__ inb, float (*inT)[264], int half,
    int m0, int Lin, int tid)
{
    const int r = tid >> 3;
    const int i = half * 32 + r;
    const int seg = tid & 7;
    const float* src = inb + (size_t)i * Lin + 2 * m0 + 32 * seg;
    float* dst = inT[r] + 1 + 32 * seg;
#pragma unroll
    for (int t = 0; t < 8; ++t) {
        const float4 v = *(const float4*)(src + 4 * t);
        float* d = dst + 4 * t;
        d[0] = v.x;
        *(float2*)(d + 1) = make_float2(v.y, v.z);
        d[3] = v.w;
    }
    if (tid < 64) {
        const int rr = tid & 31, side = tid >> 5;
        const int pl = side ? 257 : 0;
        const int p = 2 * m0 - 1 + pl;
        inT[rr][pl] = (p >= 0 && p < Lin) ? inb[(size_t)(half * 32 + rr) * Lin + p] : 0.f;
    }
}

__device__ __forceinline__ void conv_accum_half(
    const float (*inT)[264], const float* __restrict__ wpk, int ibase,
    float acc[4][8], int og, int pg)
{
    const float* wI = wpk + og * 16 + (size_t)ibase * 256;
    for (int ii = 0; ii < 32; ++ii) {
        const float* wp = wI + ii * 256;
        const float4 w0 = *(const float4*)(wp + 0);
        const float4 w1 = *(const float4*)(wp + 4);
        const float4 w2 = *(const float4*)(wp + 8);
        const float4 w3 = *(const float4*)(wp + 12);
        const float* row = inT[ii];
#pragma unroll
        for (int j = 0; j < 4; ++j) {
            const int base = 4 * pg + 64 * j;
            const float2 xa = *(const float2*)(row + base);
            const float2 xb = *(const float2*)(row + base + 2);
            const float2 xc = *(const float2*)(row + base + 4);
            acc[0][2*j]   += w0.x * xa.x + w0.y * xa.y + w0.z * xb.x + w0.w * xb.y;
            acc[1][2*j]   += w1.x * xa.x + w1.y * xa.y + w1.z * xb.x + w1.w * xb.y;
            acc[2][2*j]   += w2.x * xa.x + w2.y * xa.y + w2.z * xb.x + w2.w * xb.y;
            acc[3][2*j]   += w3.x * xa.x + w3.y * xa.y + w3.z * xb.x + w3.w * xb.y;
            acc[0][2*j+1] += w0.x * xb.x + w0.y * xb.y + w0.z * xc.x + w0.w * xc.y;
            acc[1][2*j+1] += w1.x * xb.x + w1.y * xb.y + w1.z * xc.x + w1.w * xc.y;
            acc[2][2*j+1] += w2.x * xb.x + w2.y * xb.y + w2.z * xc.x + w2.w * xc.y;
            acc[3][2*j+1] += w3.x * xb.x + w3.y * xb.y + w3.z * xc.x + w3.w * xc.y;
        }
    }
}

__device__ __forceinline__ void conv_epilogue(
    float acc[4][8], float* __restrict__ out,
    int b, int m0, int Lout, int transpose, int og, int pg)
{
    if (!transpose) {
#pragma unroll
        for (int oo = 0; oo < 4; ++oo) {
            float* ob = out + ((size_t)b * CH + og * 4 + oo) * Lout + m0 + 2 * pg;
#pragma unroll
            for (int j = 0; j < 4; ++j) {
                float2 v;
                v.x = fmaxf(acc[oo][2*j], 0.f);
                v.y = fmaxf(acc[oo][2*j+1], 0.f);
                *(float2*)(ob + 32 * j) = v;
            }
        }
    } else {
#pragma unroll
        for (int j = 0; j < 4; ++j)
#pragma unroll
            for (int h = 0; h < 2; ++h) {
                const int ml = 2 * pg + 32 * j + h;
                float* ob = out + ((size_t)b * Lout + m0 + ml) * CH + og * 4;
                float4 v;
                v.x = fmaxf(acc[0][2*j+h], 0.f);
                v.y = fmaxf(acc[1][2*j+h], 0.f);
                v.z = fmaxf(acc[2][2*j+h], 0.f);
                v.w = fmaxf(acc[3][2*j+h], 0.f);
                *(float4*)ob = v;
            }
    }
}

__global__ __launch_bounds__(256) void k_enc_conv(
    const float* __restrict__ in, const float* __restrict__ wpk,
    const float* __restrict__ bias, float* __restrict__ out,
    int Lin, int Lout, int transpose)
{
    __shared__ float inT[32][264];
    const int m0 = blockIdx.x * TILE;
    const int b = blockIdx.y;
    const int tid = threadIdx.x;
    const int og = tid >> 4, pg = tid & 15;
    const float* inb = in + (size_t)b * CH * Lin;
    float acc[4][8];
#pragma unroll
    for (int oo = 0; oo < 4; ++oo) {
        const float bv = bias[og * 4 + oo];
#pragma unroll
        for (int j = 0; j < 8; ++j) acc[oo][j] = bv;
    }
    stage_half(inb, inT, 0, m0, Lin, tid);
    __syncthreads();
    conv_accum_half(inT, wpk, 0, acc, og, pg);
    __syncthreads();
    stage_half(inb, inT, 1, m0, Lin, tid);
    __syncthreads();
    conv_accum_half(inT, wpk, 32, acc, og, pg);
    conv_epilogue(acc, out, b, m0, Lout, transpose, og, pg);
}

__global__ __launch_bounds__(256) void k_enc01(
    const float* __restrict__ x, const float* __restrict__ w0,
    const float* __restrict__ b0, const float* __restrict__ wpk0,
    const float* __restrict__ b1, float* __restrict__ out)
{
    __shared__ float xl[520];
    __shared__ float e0s[32][264];
    const int m0 = blockIdx.x * TILE;
    const int b = blockIdx.y;
    const int tid = threadIdx.x;
    const int og = tid >> 4, pg = tid & 15;
    const float* xb = x + (size_t)b * 65536;
    const int x0i = 4 * m0 - 3;
    for (int xi = tid; xi < 518; xi += 256) {
        const int q = x0i + xi;
        xl[xi] = (q >= 0 && q < 65536) ? xb[q] : 0.f;
    }
    float acc[4][8];
#pragma unroll
    for (int oo = 0; oo < 4; ++oo) {
        const float bv = b1[og * 4 + oo];
#pragma unroll
        for (int j = 0; j < 8; ++j) acc[oo][j] = bv;
    }
    const int r = tid >> 3;
    const int oct = tid & 7;
    const int pbase = 2 * m0 - 1;
    __syncthreads();
    for (int half = 0; half < 2; ++half) {
        {
            const int i = half * 32 + r;
            const float4 wv = *(const float4*)(w0 + i * 4);
            const float bv = b0[i];
            for (int t = 0; t < 33; ++t) {
                const int pl = oct * 33 + t;
                if (pl < 258) {
                    const int pe = pbase + pl;
                    const float* xp = xl + 2 * pl;
                    const float v = wv.x * xp[0] + wv.y * xp[1] + wv.z * xp[2] + wv.w * xp[3] + bv;
                    e0s[r][pl] = (pe >= 0 && pe < 32768) ? fmaxf(v, 0.f) : 0.f;
                }
            }
        }
        __syncthreads();
        conv_accum_half(e0s, wpk0, half * 32, acc, og, pg);
        __syncthreads();
    }
    conv_epilogue(acc, out, b, m0, 16384, 0, og, pg);
}

// =====================================================================
// VQ: unchanged compute; g now written as bf16 [tok][d] with pad rows.
// g row layout: (b*(1024+2) + 1 + m)*64 + d
// =====================================================================
__global__ __launch_bounds__(512) void k_vq(
    const float* __restrict__ z, const float* __restrict__ cb,
    float* __restrict__ idsf, ushort* __restrict__ g)
{
    __shared__ float c2s[1024];
    __shared__ float rval[8][64];
    __shared__ int   ridx[8][64];
    __shared__ int   widx[64];
    const int t0 = blockIdx.x * 64;
    const int tid = threadIdx.x;
    const int lane = tid & 63;
    const int wv = __builtin_amdgcn_readfirstlane(tid >> 6);

    for (int c = tid; c < 1024; c += 512) {
        const float* cp = cb + (size_t)c * 64;
        float s0 = 0.f, s1 = 0.f, s2 = 0.f, s3 = 0.f;
#pragma unroll
        for (int d = 0; d < 64; d += 4) {
            const float4 v = *(const float4*)(cp + d);
            s0 += v.x * v.x; s1 += v.y * v.y; s2 += v.z * v.z; s3 += v.w * v.w;
        }
        c2s[c] = (s0 + s1) + (s2 + s3);
    }
    float pz[64];
    {
        const float* zp = z + (size_t)(t0 + lane) * 64;
#pragma unroll
        for (int d = 0; d < 64; d += 4) {
            const float4 v = *(const float4*)(zp + d);
            pz[d] = -2.f * v.x; pz[d + 1] = -2.f * v.y;
            pz[d + 2] = -2.f * v.z; pz[d + 3] = -2.f * v.w;
        }
    }
    __syncthreads();
    float best = 3.0e38f; int bidx = 0;
    const int cbase = wv * 128;
    for (int cc = 0; cc < 128; ++cc) {
        const int code = cbase + cc;
        const float* cp = cb + (size_t)code * 64;   // uniform -> s_load
        float a0 = 0.f, a1 = 0.f, a2 = 0.f, a3 = 0.f;
#pragma unroll
        for (int d = 0; d < 64; d += 4) {
            a0 += cp[d] * pz[d];
            a1 += cp[d + 1] * pz[d + 1];
            a2 += cp[d + 2] * pz[d + 2];
            a3 += cp[d + 3] * pz[d + 3];
        }
        const float dist = c2s[code] + ((a0 + a1) + (a2 + a3));
        if (dist < best) { best = dist; bidx = code; }
    }
    rval[wv][lane] = best; ridx[wv][lane] = bidx;
    __syncthreads();
    if (tid < 64) {
        float bv = rval[0][tid]; int bi = ridx[0][tid];
#pragma unroll
        for (int k2 = 1; k2 < 8; ++k2) {
            const float v = rval[k2][tid];
            if (v < bv) { bv = v; bi = ridx[k2][tid]; }
        }
        widx[tid] = bi;
        idsf[t0 + tid] = (float)bi;
    }
    __syncthreads();
    const int bb = t0 >> 10;
    const int mb = t0 & 1023;
    ushort* gb = g + ((size_t)bb * 1026 + 1 + mb) * 64;
    for (int e = tid; e < 4096; e += 512) {
        const int d = e & 63;
        const int tok = e >> 6;
        gb[(size_t)tok * 64 + d] = f2bf(cb[(size_t)widx[tok] * 64 + d]);
    }
    // pad rows (zeros) at m=-1 / m=1024 for this batch
    if (mb == 0 && tid < 16) {
        ushort4 zz = {0, 0, 0, 0};
        *(ushort4*)(g + ((size_t)bb * 1026) * 64 + tid * 4) = zz;
    }
    if (mb == 960 && tid < 16) {
        ushort4 zz = {0, 0, 0, 0};
        *(ushort4*)(g + ((size_t)bb * 1026 + 1025) * 64 + tid * 4) = zz;
    }
}

// =====================================================================
// DECODER v3: inter-layer format = padded bf16 [n][ch] (the MFMA B layout).
// B-fragments load straight from global; no X staging, no LDS in k_dec2.
// Afrag layout [L][tap][m][kt][lane][j] unchanged.
// =====================================================================
__global__ __launch_bounds__(256) void k_prepack(
    const float* __restrict__ dec_w, ushort* __restrict__ Afrag)
{
    const int idx = blockIdx.x * 256 + threadIdx.x;   // 81920
    const int j    = idx & 7;
    const int lane = (idx >> 3) & 63;
    const int kt   = (idx >> 9) & 1;
    const int m    = (idx >> 10) & 3;
    const int tap  = (idx >> 12) & 3;
    const int L    = idx >> 14;
    const int o = m * 16 + (lane & 15);
    const int i = kt * 32 + ((lane >> 4) << 3) + j;
    Afrag[idx] = f2bf(dec_w[(((size_t)L * 64 + i) * 64 + o) * 4 + tap]);
}

// compute 8 accumulators; B-fragments direct from padded global Xb (row u*64)
__device__ __forceinline__ void dec_mfma_compute_g(
    const ushort* __restrict__ Xb, const ushort* __restrict__ AfragL,
    int u0, int tid, f32x4 accE[4], f32x4 accO[4],
    int& ul_out, int& kg_out)
{
    const int lane = tid & 63;
    const int wave = tid >> 6;
    const int col = lane & 15, kg = lane >> 4;
    const int ul = wave * 16 + col;
    const ushort* basep = Xb + (size_t)(u0 + ul) * 64 + kg * 8;
    s16x8 Bm1[2], B0[2], Bp1[2];
#pragma unroll
    for (int kt = 0; kt < 2; ++kt) {
        Bm1[kt] = *(const s16x8*)(basep - 64 + kt * 32);
        B0[kt]  = *(const s16x8*)(basep + kt * 32);
        Bp1[kt] = *(const s16x8*)(basep + 64 + kt * 32);
    }
    const s16x8* Af = (const s16x8*)AfragL;
#pragma unroll
    for (int m = 0; m < 4; ++m) {
        f32x4 aE = {0.f, 0.f, 0.f, 0.f};
        f32x4 aO = {0.f, 0.f, 0.f, 0.f};
#pragma unroll
        for (int kt = 0; kt < 2; ++kt) {
            aE = __builtin_amdgcn_mfma_f32_16x16x32_bf16(
                Af[((1 * 4 + m) * 2 + kt) * 64 + lane], B0[kt], aE, 0, 0, 0);
            aE = __builtin_amdgcn_mfma_f32_16x16x32_bf16(
                Af[((3 * 4 + m) * 2 + kt) * 64 + lane], Bm1[kt], aE, 0, 0, 0);
            aO = __builtin_amdgcn_mfma_f32_16x16x32_bf16(
                Af[((2 * 4 + m) * 2 + kt) * 64 + lane], B0[kt], aO, 0, 0, 0);
            aO = __builtin_amdgcn_mfma_f32_16x16x32_bf16(
                Af[((0 * 4 + m) * 2 + kt) * 64 + lane], Bp1[kt], aO, 0, 0, 0);
        }
        accE[m] = aE;
        accO[m] = aO;
    }
    ul_out = ul; kg_out = kg;
}

// convT layer: padded bf16 [u][ch] in -> padded bf16 [n][ch] out
__global__ __launch_bounds__(256) void k_dec2(
    const ushort* __restrict__ Xt, const ushort* __restrict__ AfragL,
    const float* __restrict__ bias, ushort* __restrict__ Yt, int Lin)
{
    const int u0 = blockIdx.x * 64;
    const int b  = blockIdx.y;
    const int tid = threadIdx.x;
    const int Lout = Lin * 2;
    const ushort* Xb = Xt + ((size_t)b * (Lin + 2) + 1) * 64;
    ushort* Yb = Yt + ((size_t)b * (Lout + 2) + 1) * 64;

    f32x4 accE[4], accO[4];
    int ul, kg;
    dec_mfma_compute_g(Xb, AfragL, u0, tid, accE, accO, ul, kg);
    const size_t n2 = 2 * (size_t)(u0 + ul);
#pragma unroll
    for (int m = 0; m < 4; ++m) {
        const float4 bm4 = *(const float4*)(bias + m * 16 + kg * 4);
        const float bb[4] = {bm4.x, bm4.y, bm4.z, bm4.w};
        ushort4 pe, po;
        pe.x = f2bf(fmaxf(accE[m][0] + bb[0], 0.f));
        pe.y = f2bf(fmaxf(accE[m][1] + bb[1], 0.f));
        pe.z = f2bf(fmaxf(accE[m][2] + bb[2], 0.f));
        pe.w = f2bf(fmaxf(accE[m][3] + bb[3], 0.f));
        po.x = f2bf(fmaxf(accO[m][0] + bb[0], 0.f));
        po.y = f2bf(fmaxf(accO[m][1] + bb[1], 0.f));
        po.z = f2bf(fmaxf(accO[m][2] + bb[2], 0.f));
        po.w = f2bf(fmaxf(accO[m][3] + bb[3], 0.f));
        *(ushort4*)(Yb + n2 * 64 + m * 16 + kg * 4) = pe;
        *(ushort4*)(Yb + (n2 + 1) * 64 + m * 16 + kg * 4) = po;
    }
    // pad rows for next layer
    if (blockIdx.x == 0 && tid < 16) {
        ushort4 zz = {0, 0, 0, 0};
        *(ushort4*)(Yt + ((size_t)b * (Lout + 2)) * 64 + tid * 4) = zz;
    }
    if (u0 + 64 >= Lin && tid < 16) {
        ushort4 zz = {0, 0, 0, 0};
        *(ushort4*)(Yb + (size_t)Lout * 64 + tid * 4) = zz;
    }
}

// fused dec4 + last convT: d4 tile in LDS, y written directly
__global__ __launch_bounds__(256) void k_dec4y(
    const ushort* __restrict__ Xt, const ushort* __restrict__ AfragL,
    const float* __restrict__ w4, const float* __restrict__ bias,
    const float* __restrict__ wl, const float* __restrict__ blp,
    float* __restrict__ y)
{
    __shared__ float d4s[64][130];   // col vl = v - (2u0-1); 0,129 = halo
    const int u0 = blockIdx.x * 64;
    const int b  = blockIdx.y;
    const int tid = threadIdx.x;
    const int Lin = 16384;
    const ushort* Xb = Xt + ((size_t)b * (Lin + 2) + 1) * 64;

    f32x4 accE[4], accO[4];
    int ul, kg;
    dec_mfma_compute_g(Xb, AfragL, u0, tid, accE, accO, ul, kg);
#pragma unroll
    for (int m = 0; m < 4; ++m) {
        const float4 bm4 = *(const float4*)(bias + m * 16 + kg * 4);
        const float bb[4] = {bm4.x, bm4.y, bm4.z, bm4.w};
#pragma unroll
        for (int r = 0; r < 4; ++r) {
            const int o = m * 16 + kg * 4 + r;
            d4s[o][2 * ul + 1] = fmaxf(accE[m][r] + bb[r], 0.f);
            d4s[o][2 * ul + 2] = fmaxf(accO[m][r] + bb[r], 0.f);
        }
    }
    // halo cols from padded global rows; 2 partial accumulators
    {
        const int side = tid >> 7;
        const int o = (tid >> 1) & 63;
        const int half = tid & 1;
        const int ib = half * 32;
        float p0 = 0.f, p1 = 0.f;
        const ushort* r0 = Xb + (size_t)(side ? (u0 + 64) : (u0 - 1)) * 64;
        const ushort* r1 = Xb + (size_t)(side ? (u0 + 63) : u0) * 64;
        const int tA = side ? 1 : 2;   // weight index for r0
        const int tB = side ? 3 : 0;   // weight index for r1
        for (int i = ib; i < ib + 32; i += 2) {
            const float* wpa = w4 + ((size_t)i * 64 + o) * 4;
            const float* wpb = w4 + ((size_t)(i + 1) * 64 + o) * 4;
            p0 += wpa[tA] * bf2f(r0[i]) + wpa[tB] * bf2f(r1[i]);
            p1 += wpb[tA] * bf2f(r0[i + 1]) + wpb[tB] * bf2f(r1[i + 1]);
        }
        float part = p0 + p1;
        part += __shfl_xor(part, 1);
        if (half == 0) {
            const float acc = bias[o] + part;
            if (side == 0) d4s[o][0]   = (u0 > 0)          ? fmaxf(acc, 0.f) : 0.f;
            else           d4s[o][129] = (u0 + 64 < 16384) ? fmaxf(acc, 0.f) : 0.f;
        }
    }
    __syncthreads();
    // y: n = 4*u0 + tid; v=n>>1 -> vl=(tid>>1)+1 in [1,128]; 4 partial chains
    {
        const int odd = tid & 1;
        const int vl = (tid >> 1) + 1;
        float a0 = 0.f, a1 = 0.f, a2 = 0.f, a3 = 0.f;
        for (int o = 0; o < 64; o += 4) {
            const float4 w0 = *(const float4*)(wl + (o + 0) * 4);
            const float4 w1 = *(const float4*)(wl + (o + 1) * 4);
            const float4 w2 = *(const float4*)(wl + (o + 2) * 4);
            const float4 w3 = *(const float4*)(wl + (o + 3) * 4);
            const float xv0 = d4s[o + 0][vl], xn0 = d4s[o + 0][odd ? vl + 1 : vl - 1];
            const float xv1 = d4s[o + 1][vl], xn1 = d4s[o + 1][odd ? vl + 1 : vl - 1];
            const float xv2 = d4s[o + 2][vl], xn2 = d4s[o + 2][odd ? vl + 1 : vl - 1];
            const float xv3 = d4s[o + 3][vl], xn3 = d4s[o + 3][odd ? vl + 1 : vl - 1];
            a0 += odd ? (w0.z * xv0 + w0.x * xn0) : (w0.y * xv0 + w0.w * xn0);
            a1 += odd ? (w1.z * xv1 + w1.x * xn1) : (w1.y * xv1 + w1.w * xn1);
            a2 += odd ? (w2.z * xv2 + w2.x * xn2) : (w2.y * xv2 + w2.w * xn2);
            a3 += odd ? (w3.z * xv3 + w3.x * xn3) : (w3.y * xv3 + w3.w * xn3);
        }
        y[(size_t)b * 65536 + 4 * u0 + tid] = blp[0] + ((a0 + a1) + (a2 + a3));
    }
}

extern "C" void kernel_launch(void* const* d_in, const int* in_sizes, int n_in,
                              void* d_out, int out_size, void* d_ws, size_t ws_size,
                              hipStream_t stream) {
    const float* x      = (const float*)d_in[0];
    const float* enc_w0 = (const float*)d_in[1];
    const float* enc_w  = (const float*)d_in[2];   // (5,64,64,4)
    const float* enc_b  = (const float*)d_in[3];   // (6,64)
    const float* cb     = (const float*)d_in[4];   // (1024,64)
    const float* dec_w  = (const float*)d_in[5];   // (5,64,64,4) [in][out][k]
    const float* dec_wl = (const float*)d_in[6];   // (64,1,4)
    const float* dec_b  = (const float*)d_in[7];   // (5,64)
    const float* dec_bl = (const float*)d_in[8];   // (1,)
    float* y    = (float*)d_out;                   // (16,1,65536)
    float* z_e  = y + 1048576;                     // (16384,64)
    float* idsf = y + 2097152;                     // (16384,)

    // workspace overlay: A = 16.7M floats (67MB), Bf = 8.4M floats (33.6MB)
    float* A  = (float*)d_ws;
    float* Bf = A + 16777216;

    // Scratch in y batches 14-15: encW dead after encoder; Afrag used by
    // decoder L0-L3; layer-4 slice d2d-copied into Bf before k_dec4y
    // overwrites all of y.
    float*  encW  = y + 14 * 65536;
    ushort* Afrag = (ushort*)(encW + 81920);

    k_prepack_enc<<<dim3(320), 256, 0, stream>>>(enc_w, encW);
    k_prepack<<<dim3(320), 256, 0, stream>>>(dec_w, Afrag);

    // encoder (fp32): x -> h1(A) -> h2(Bf) -> h3(A) -> h4(Bf) -> z_e
    k_enc01<<<dim3(128, 16), 256, 0, stream>>>(x, enc_w0, enc_b, encW, enc_b + 64, A);
    k_enc_conv<<<dim3(64, 16), 256, 0, stream>>>(A,  encW + 1 * 16384, enc_b + 2 * 64, Bf, 16384, 8192, 0);
    k_enc_conv<<<dim3(32, 16), 256, 0, stream>>>(Bf, encW + 2 * 16384, enc_b + 3 * 64, A,  8192,  4096, 0);
    k_enc_conv<<<dim3(16, 16), 256, 0, stream>>>(A,  encW + 3 * 16384, enc_b + 4 * 64, Bf, 4096,  2048, 0);
    k_enc_conv<<<dim3(8, 16),  256, 0, stream>>>(Bf, encW + 4 * 16384, enc_b + 5 * 64, z_e, 2048, 1024, 1);
    // vector quantize -> g (padded bf16 [tok][d]) in A
    k_vq<<<256, 512, 0, stream>>>(z_e, cb, idsf, (ushort*)A);

    // decoder (bf16 MFMA v3, transposed bf16 inter-layer format)
    // g(A) -> L0(Bf) -> L1(A) -> L2(Bf) -> L3(A) -> dec4y -> y
    k_dec2<<<dim3(16, 16),  256, 0, stream>>>((const ushort*)A,  Afrag + 0 * 16384, dec_b + 0 * 64, (ushort*)Bf, 1024);
    k_dec2<<<dim3(32, 16),  256, 0, stream>>>((const ushort*)Bf, Afrag + 1 * 16384, dec_b + 1 * 64, (ushort*)A,  2048);
    k_dec2<<<dim3(64, 16),  256, 0, stream>>>((const ushort*)A,  Afrag + 2 * 16384, dec_b + 2 * 64, (ushort*)Bf, 4096);
    k_dec2<<<dim3(128, 16), 256, 0, stream>>>((const ushort*)Bf, Afrag + 3 * 16384, dec_b + 3 * 64, (ushort*)A,  8192);
    // move layer-4 A-frags out of y (k_dec4y overwrites all of y)
    (void)hipMemcpyAsync(Bf, Afrag + 4 * 16384, 16384 * sizeof(ushort),
                         hipMemcpyDeviceToDevice, stream);
    k_dec4y<<<dim3(256, 16), 256, 0, stream>>>((const ushort*)A, (const ushort*)Bf,
                                               dec_w + 4 * 16384, dec_b + 4 * 64,
                                               dec_wl, dec_bl, y);
}

// Round 12
// 523.215 us; speedup vs baseline: 1.3685x; 1.0200x over previous
//
#include <hip/hip_runtime.h>

#define CH 64
#define TILE 128

typedef short s16x8 __attribute__((ext_vector_type(8)));
typedef float f32x4 __attribute__((ext_vector_type(4)));

static __device__ __forceinline__ ushort f2bf(float f) {
    union { float f; uint u; } v; v.f = f;
    const uint r = (v.u + 0x7FFFu + ((v.u >> 16) & 1u)) >> 16;
    return (ushort)r;
}
static __device__ __forceinline__ float bf2f(ushort u) {
    union { uint u; float f; } v; v.u = ((uint)u) << 16; return v.f;
}

// =====================================================================
// Prepack encoder weights (5,64,64,4) [o][i][tau] -> [L][i][o][tau]
// =====================================================================
__global__ __launch_bounds__(256) void k_prepack_enc(
    const float* __restrict__ enc_w, float* __restrict__ encW)
{
    const int idx = blockIdx.x * 256 + threadIdx.x;   // 81920
    const int tau = idx & 3;
    const int o = (idx >> 2) & 63;
    const int i = (idx >> 8) & 63;
    const int L = idx >> 14;
    encW[idx] = enc_w[(((size_t)L * 64 + o) * 64 + i) * 4 + tau];
}

// =====================================================================
// ENCODER (fp32): 128-pos tile, 256 threads; input staged in LDS
// 16 channels per phase (17KB LDS -> 8 blocks/CU, 2x occupancy).
// =====================================================================
__device__ __forceinline__ void stage_q(
    const float* __restrict__ inb, float (*inT)[264], int q,
    int m0, int Lin, int tid)
{
    const int r = tid >> 4;            // 0..15
    const int i = q * 16 + r;
    const int seg = tid & 15;
    // interior pl = 1 + 16*seg + 4t + d : p = 2*m0 + 16*seg + ..., in bounds
    const float* src = inb + (size_t)i * Lin + 2 * m0 + 16 * seg;
    float* dst = inT[r] + 1 + 16 * seg;
#pragma unroll
    for (int t = 0; t < 4; ++t) {
        const float4 v = *(const float4*)(src + 4 * t);
        float* d = dst + 4 * t;
        d[0] = v.x;
        *(float2*)(d + 1) = make_float2(v.y, v.z);
        d[3] = v.w;
    }
    if (tid < 32) {                    // edges pl=0 and pl=257
        const int rr = tid & 15, side = tid >> 4;
        const int pl = side ? 257 : 0;
        const int p = 2 * m0 - 1 + pl;
        inT[rr][pl] = (p >= 0 && p < Lin) ? inb[(size_t)(q * 16 + rr) * Lin + p] : 0.f;
    }
}

__device__ __forceinline__ void conv_accum_q(
    const float (*inT)[264], const float* __restrict__ wpk, int ibase,
    float acc[4][8], int og, int pg)
{
    const float* wI = wpk + og * 16 + (size_t)ibase * 256;
    for (int ii = 0; ii < 16; ++ii) {
        const float* wp = wI + ii * 256;
        const float4 w0 = *(const float4*)(wp + 0);
        const float4 w1 = *(const float4*)(wp + 4);
        const float4 w2 = *(const float4*)(wp + 8);
        const float4 w3 = *(const float4*)(wp + 12);
        const float* row = inT[ii];
#pragma unroll
        for (int j = 0; j < 4; ++j) {
            const int base = 4 * pg + 64 * j;
            const float2 xa = *(const float2*)(row + base);
            const float2 xb = *(const float2*)(row + base + 2);
            const float2 xc = *(const float2*)(row + base + 4);
            acc[0][2*j]   += w0.x * xa.x + w0.y * xa.y + w0.z * xb.x + w0.w * xb.y;
            acc[1][2*j]   += w1.x * xa.x + w1.y * xa.y + w1.z * xb.x + w1.w * xb.y;
            acc[2][2*j]   += w2.x * xa.x + w2.y * xa.y + w2.z * xb.x + w2.w * xb.y;
            acc[3][2*j]   += w3.x * xa.x + w3.y * xa.y + w3.z * xb.x + w3.w * xb.y;
            acc[0][2*j+1] += w0.x * xb.x + w0.y * xb.y + w0.z * xc.x + w0.w * xc.y;
            acc[1][2*j+1] += w1.x * xb.x + w1.y * xb.y + w1.z * xc.x + w1.w * xc.y;
            acc[2][2*j+1] += w2.x * xb.x + w2.y * xb.y + w2.z * xc.x + w2.w * xc.y;
            acc[3][2*j+1] += w3.x * xb.x + w3.y * xb.y + w3.z * xc.x + w3.w * xc.y;
        }
    }
}

__device__ __forceinline__ void conv_epilogue(
    float acc[4][8], float* __restrict__ out,
    int b, int m0, int Lout, int transpose, int og, int pg)
{
    if (!transpose) {
#pragma unroll
        for (int oo = 0; oo < 4; ++oo) {
            float* ob = out + ((size_t)b * CH + og * 4 + oo) * Lout + m0 + 2 * pg;
#pragma unroll
            for (int j = 0; j < 4; ++j) {
                float2 v;
                v.x = fmaxf(acc[oo][2*j], 0.f);
                v.y = fmaxf(acc[oo][2*j+1], 0.f);
                *(float2*)(ob + 32 * j) = v;
            }
        }
    } else {
#pragma unroll
        for (int j = 0; j < 4; ++j)
#pragma unroll
            for (int h = 0; h < 2; ++h) {
                const int ml = 2 * pg + 32 * j + h;
                float* ob = out + ((size_t)b * Lout + m0 + ml) * CH + og * 4;
                float4 v;
                v.x = fmaxf(acc[0][2*j+h], 0.f);
                v.y = fmaxf(acc[1][2*j+h], 0.f);
                v.z = fmaxf(acc[2][2*j+h], 0.f);
                v.w = fmaxf(acc[3][2*j+h], 0.f);
                *(float4*)ob = v;
            }
    }
}

__global__ __launch_bounds__(256) void k_enc_conv(
    const float* __restrict__ in, const float* __restrict__ wpk,
    const float* __restrict__ bias, float* __restrict__ out,
    int Lin, int Lout, int transpose)
{
    __shared__ float inT[16][264];
    const int m0 = blockIdx.x * TILE;
    const int b = blockIdx.y;
    const int tid = threadIdx.x;
    const int og = tid >> 4, pg = tid & 15;
    const float* inb = in + (size_t)b * CH * Lin;
    float acc[4][8];
#pragma unroll
    for (int oo = 0; oo < 4; ++oo) {
        const float bv = bias[og * 4 + oo];
#pragma unroll
        for (int j = 0; j < 8; ++j) acc[oo][j] = bv;
    }
    for (int q = 0; q < 4; ++q) {
        stage_q(inb, inT, q, m0, Lin, tid);
        __syncthreads();
        conv_accum_q(inT, wpk, q * 16, acc, og, pg);
        __syncthreads();
    }
    conv_epilogue(acc, out, b, m0, Lout, transpose, og, pg);
}

__global__ __launch_bounds__(256) void k_enc01(
    const float* __restrict__ x, const float* __restrict__ w0,
    const float* __restrict__ b0, const float* __restrict__ wpk0,
    const float* __restrict__ b1, float* __restrict__ out)
{
    __shared__ float xl[520];
    __shared__ float e0s[16][264];
    const int m0 = blockIdx.x * TILE;
    const int b = blockIdx.y;
    const int tid = threadIdx.x;
    const int og = tid >> 4, pg = tid & 15;
    const float* xb = x + (size_t)b * 65536;
    const int x0i = 4 * m0 - 3;
    for (int xi = tid; xi < 518; xi += 256) {
        const int q = x0i + xi;
        xl[xi] = (q >= 0 && q < 65536) ? xb[q] : 0.f;
    }
    float acc[4][8];
#pragma unroll
    for (int oo = 0; oo < 4; ++oo) {
        const float bv = b1[og * 4 + oo];
#pragma unroll
        for (int j = 0; j < 8; ++j) acc[oo][j] = bv;
    }
    const int r = tid >> 4;            // e0 row worker 0..15
    const int oct = tid & 15;          // 16 slots x 17 values
    const int pbase = 2 * m0 - 1;      // e0-pos of pl=0; e0 length = 32768
    __syncthreads();
    for (int q = 0; q < 4; ++q) {
        {
            const int i = q * 16 + r;
            const float4 wv = *(const float4*)(w0 + i * 4);
            const float bv = b0[i];
            for (int t = 0; t < 17; ++t) {
                const int pl = oct * 17 + t;
                if (pl < 258) {
                    const int pe = pbase + pl;
                    const float* xp = xl + 2 * pl;
                    const float v = wv.x * xp[0] + wv.y * xp[1] + wv.z * xp[2] + wv.w * xp[3] + bv;
                    e0s[r][pl] = (pe >= 0 && pe < 32768) ? fmaxf(v, 0.f) : 0.f;
                }
            }
        }
        __syncthreads();
        conv_accum_q(e0s, wpk0, q * 16, acc, og, pg);
        __syncthreads();
    }
    conv_epilogue(acc, out, b, m0, 16384, 0, og, pg);
}

// =====================================================================
// VQ — unchanged (g written as padded bf16 [tok][d])
// =====================================================================
__global__ __launch_bounds__(512) void k_vq(
    const float* __restrict__ z, const float* __restrict__ cb,
    float* __restrict__ idsf, ushort* __restrict__ g)
{
    __shared__ float c2s[1024];
    __shared__ float rval[8][64];
    __shared__ int   ridx[8][64];
    __shared__ int   widx[64];
    const int t0 = blockIdx.x * 64;
    const int tid = threadIdx.x;
    const int lane = tid & 63;
    const int wv = __builtin_amdgcn_readfirstlane(tid >> 6);

    for (int c = tid; c < 1024; c += 512) {
        const float* cp = cb + (size_t)c * 64;
        float s0 = 0.f, s1 = 0.f, s2 = 0.f, s3 = 0.f;
#pragma unroll
        for (int d = 0; d < 64; d += 4) {
            const float4 v = *(const float4*)(cp + d);
            s0 += v.x * v.x; s1 += v.y * v.y; s2 += v.z * v.z; s3 += v.w * v.w;
        }
        c2s[c] = (s0 + s1) + (s2 + s3);
    }
    float pz[64];
    {
        const float* zp = z + (size_t)(t0 + lane) * 64;
#pragma unroll
        for (int d = 0; d < 64; d += 4) {
            const float4 v = *(const float4*)(zp + d);
            pz[d] = -2.f * v.x; pz[d + 1] = -2.f * v.y;
            pz[d + 2] = -2.f * v.z; pz[d + 3] = -2.f * v.w;
        }
    }
    __syncthreads();
    float best = 3.0e38f; int bidx = 0;
    const int cbase = wv * 128;
    for (int cc = 0; cc < 128; ++cc) {
        const int code = cbase + cc;
        const float* cp = cb + (size_t)code * 64;   // uniform -> s_load
        float a0 = 0.f, a1 = 0.f, a2 = 0.f, a3 = 0.f;
#pragma unroll
        for (int d = 0; d < 64; d += 4) {
            a0 += cp[d] * pz[d];
            a1 += cp[d + 1] * pz[d + 1];
            a2 += cp[d + 2] * pz[d + 2];
            a3 += cp[d + 3] * pz[d + 3];
        }
        const float dist = c2s[code] + ((a0 + a1) + (a2 + a3));
        if (dist < best) { best = dist; bidx = code; }
    }
    rval[wv][lane] = best; ridx[wv][lane] = bidx;
    __syncthreads();
    if (tid < 64) {
        float bv = rval[0][tid]; int bi = ridx[0][tid];
#pragma unroll
        for (int k2 = 1; k2 < 8; ++k2) {
            const float v = rval[k2][tid];
            if (v < bv) { bv = v; bi = ridx[k2][tid]; }
        }
        widx[tid] = bi;
        idsf[t0 + tid] = (float)bi;
    }
    __syncthreads();
    const int bb = t0 >> 10;
    const int mb = t0 & 1023;
    ushort* gb = g + ((size_t)bb * 1026 + 1 + mb) * 64;
    for (int e = tid; e < 4096; e += 512) {
        const int d = e & 63;
        const int tok = e >> 6;
        gb[(size_t)tok * 64 + d] = f2bf(cb[(size_t)widx[tok] * 64 + d]);
    }
    if (mb == 0 && tid < 16) {
        ushort4 zz = {0, 0, 0, 0};
        *(ushort4*)(g + ((size_t)bb * 1026) * 64 + tid * 4) = zz;
    }
    if (mb == 960 && tid < 16) {
        ushort4 zz = {0, 0, 0, 0};
        *(ushort4*)(g + ((size_t)bb * 1026 + 1025) * 64 + tid * 4) = zz;
    }
}

// =====================================================================
// DECODER v3.1: padded bf16 [n][ch] inter-layer format; k_dec2 now
// 1-wave blocks (64 threads, 16 cols) for latency hiding.
// =====================================================================
__global__ __launch_bounds__(256) void k_prepack(
    const float* __restrict__ dec_w, ushort* __restrict__ Afrag)
{
    const int idx = blockIdx.x * 256 + threadIdx.x;   // 81920
    const int j    = idx & 7;
    const int lane = (idx >> 3) & 63;
    const int kt   = (idx >> 9) & 1;
    const int m    = (idx >> 10) & 3;
    const int tap  = (idx >> 12) & 3;
    const int L    = idx >> 14;
    const int o = m * 16 + (lane & 15);
    const int i = kt * 32 + ((lane >> 4) << 3) + j;
    Afrag[idx] = f2bf(dec_w[(((size_t)L * 64 + i) * 64 + o) * 4 + tap]);
}

// compute 8 accumulators; B-fragments direct from padded global Xb (row u*64)
__device__ __forceinline__ void dec_mfma_compute_g(
    const ushort* __restrict__ Xb, const ushort* __restrict__ AfragL,
    int u0, int tid, f32x4 accE[4], f32x4 accO[4],
    int& ul_out, int& kg_out)
{
    const int lane = tid & 63;
    const int wave = tid >> 6;
    const int col = lane & 15, kg = lane >> 4;
    const int ul = wave * 16 + col;
    const ushort* basep = Xb + (size_t)(u0 + ul) * 64 + kg * 8;
    s16x8 Bm1[2], B0[2], Bp1[2];
#pragma unroll
    for (int kt = 0; kt < 2; ++kt) {
        Bm1[kt] = *(const s16x8*)(basep - 64 + kt * 32);
        B0[kt]  = *(const s16x8*)(basep + kt * 32);
        Bp1[kt] = *(const s16x8*)(basep + 64 + kt * 32);
    }
    const s16x8* Af = (const s16x8*)AfragL;
#pragma unroll
    for (int m = 0; m < 4; ++m) {
        f32x4 aE = {0.f, 0.f, 0.f, 0.f};
        f32x4 aO = {0.f, 0.f, 0.f, 0.f};
#pragma unroll
        for (int kt = 0; kt < 2; ++kt) {
            aE = __builtin_amdgcn_mfma_f32_16x16x32_bf16(
                Af[((1 * 4 + m) * 2 + kt) * 64 + lane], B0[kt], aE, 0, 0, 0);
            aE = __builtin_amdgcn_mfma_f32_16x16x32_bf16(
                Af[((3 * 4 + m) * 2 + kt) * 64 + lane], Bm1[kt], aE, 0, 0, 0);
            aO = __builtin_amdgcn_mfma_f32_16x16x32_bf16(
                Af[((2 * 4 + m) * 2 + kt) * 64 + lane], B0[kt], aO, 0, 0, 0);
            aO = __builtin_amdgcn_mfma_f32_16x16x32_bf16(
                Af[((0 * 4 + m) * 2 + kt) * 64 + lane], Bp1[kt], aO, 0, 0, 0);
        }
        accE[m] = aE;
        accO[m] = aO;
    }
    ul_out = ul; kg_out = kg;
}

// convT layer: padded bf16 [u][ch] in -> padded bf16 [n][ch] out.
// 64-thread (1-wave) blocks, 16 u-cols each: no LDS, no barriers.
__global__ __launch_bounds__(64) void k_dec2(
    const ushort* __restrict__ Xt, const ushort* __restrict__ AfragL,
    const float* __restrict__ bias, ushort* __restrict__ Yt, int Lin)
{
    const int u0 = blockIdx.x * 16;
    const int b  = blockIdx.y;
    const int tid = threadIdx.x;
    const int Lout = Lin * 2;
    const ushort* Xb = Xt + ((size_t)b * (Lin + 2) + 1) * 64;
    ushort* Yb = Yt + ((size_t)b * (Lout + 2) + 1) * 64;

    f32x4 accE[4], accO[4];
    int ul, kg;
    dec_mfma_compute_g(Xb, AfragL, u0, tid, accE, accO, ul, kg);
    const size_t n2 = 2 * (size_t)(u0 + ul);
#pragma unroll
    for (int m = 0; m < 4; ++m) {
        const float4 bm4 = *(const float4*)(bias + m * 16 + kg * 4);
        const float bb[4] = {bm4.x, bm4.y, bm4.z, bm4.w};
        ushort4 pe, po;
        pe.x = f2bf(fmaxf(accE[m][0] + bb[0], 0.f));
        pe.y = f2bf(fmaxf(accE[m][1] + bb[1], 0.f));
        pe.z = f2bf(fmaxf(accE[m][2] + bb[2], 0.f));
        pe.w = f2bf(fmaxf(accE[m][3] + bb[3], 0.f));
        po.x = f2bf(fmaxf(accO[m][0] + bb[0], 0.f));
        po.y = f2bf(fmaxf(accO[m][1] + bb[1], 0.f));
        po.z = f2bf(fmaxf(accO[m][2] + bb[2], 0.f));
        po.w = f2bf(fmaxf(accO[m][3] + bb[3], 0.f));
        *(ushort4*)(Yb + n2 * 64 + m * 16 + kg * 4) = pe;
        *(ushort4*)(Yb + (n2 + 1) * 64 + m * 16 + kg * 4) = po;
    }
    // pad rows for next layer
    if (blockIdx.x == 0 && tid < 16) {
        ushort4 zz = {0, 0, 0, 0};
        *(ushort4*)(Yt + ((size_t)b * (Lout + 2)) * 64 + tid * 4) = zz;
    }
    if (u0 + 16 >= Lin && tid < 16) {
        ushort4 zz = {0, 0, 0, 0};
        *(ushort4*)(Yb + (size_t)Lout * 64 + tid * 4) = zz;
    }
}

// fused dec4 + last convT: d4 tile in LDS, y written directly (unchanged)
__global__ __launch_bounds__(256) void k_dec4y(
    const ushort* __restrict__ Xt, const ushort* __restrict__ AfragL,
    const float* __restrict__ w4, const float* __restrict__ bias,
    const float* __restrict__ wl, const float* __restrict__ blp,
    float* __restrict__ y)
{
    __shared__ float d4s[64][130];   // col vl = v - (2u0-1); 0,129 = halo
    const int u0 = blockIdx.x * 64;
    const int b  = blockIdx.y;
    const int tid = threadIdx.x;
    const int Lin = 16384;
    const ushort* Xb = Xt + ((size_t)b * (Lin + 2) + 1) * 64;

    f32x4 accE[4], accO[4];
    int ul, kg;
    dec_mfma_compute_g(Xb, AfragL, u0, tid, accE, accO, ul, kg);
#pragma unroll
    for (int m = 0; m < 4; ++m) {
        const float4 bm4 = *(const float4*)(bias + m * 16 + kg * 4);
        const float bb[4] = {bm4.x, bm4.y, bm4.z, bm4.w};
#pragma unroll
        for (int r = 0; r < 4; ++r) {
            const int o = m * 16 + kg * 4 + r;
            d4s[o][2 * ul + 1] = fmaxf(accE[m][r] + bb[r], 0.f);
            d4s[o][2 * ul + 2] = fmaxf(accO[m][r] + bb[r], 0.f);
        }
    }
    {
        const int side = tid >> 7;
        const int o = (tid >> 1) & 63;
        const int half = tid & 1;
        const int ib = half * 32;
        float p0 = 0.f, p1 = 0.f;
        const ushort* r0 = Xb + (size_t)(side ? (u0 + 64) : (u0 - 1)) * 64;
        const ushort* r1 = Xb + (size_t)(side ? (u0 + 63) : u0) * 64;
        const int tA = side ? 1 : 2;
        const int tB = side ? 3 : 0;
        for (int i = ib; i < ib + 32; i += 2) {
            const float* wpa = w4 + ((size_t)i * 64 + o) * 4;
            const float* wpb = w4 + ((size_t)(i + 1) * 64 + o) * 4;
            p0 += wpa[tA] * bf2f(r0[i]) + wpa[tB] * bf2f(r1[i]);
            p1 += wpb[tA] * bf2f(r0[i + 1]) + wpb[tB] * bf2f(r1[i + 1]);
        }
        float part = p0 + p1;
        part += __shfl_xor(part, 1);
        if (half == 0) {
            const float acc = bias[o] + part;
            if (side == 0) d4s[o][0]   = (u0 > 0)          ? fmaxf(acc, 0.f) : 0.f;
            else           d4s[o][129] = (u0 + 64 < 16384) ? fmaxf(acc, 0.f) : 0.f;
        }
    }
    __syncthreads();
    {
        const int odd = tid & 1;
        const int vl = (tid >> 1) + 1;
        float a0 = 0.f, a1 = 0.f, a2 = 0.f, a3 = 0.f;
        for (int o = 0; o < 64; o += 4) {
            const float4 w0 = *(const float4*)(wl + (o + 0) * 4);
            const float4 w1 = *(const float4*)(wl + (o + 1) * 4);
            const float4 w2 = *(const float4*)(wl + (o + 2) * 4);
            const float4 w3 = *(const float4*)(wl + (o + 3) * 4);
            const float xv0 = d4s[o + 0][vl], xn0 = d4s[o + 0][odd ? vl + 1 : vl - 1];
            const float xv1 = d4s[o + 1][vl], xn1 = d4s[o + 1][odd ? vl + 1 : vl - 1];
            const float xv2 = d4s[o + 2][vl], xn2 = d4s[o + 2][odd ? vl + 1 : vl - 1];
            const float xv3 = d4s[o + 3][vl], xn3 = d4s[o + 3][odd ? vl + 1 : vl - 1];
            a0 += odd ? (w0.z * xv0 + w0.x * xn0) : (w0.y * xv0 + w0.w * xn0);
            a1 += odd ? (w1.z * xv1 + w1.x * xn1) : (w1.y * xv1 + w1.w * xn1);
            a2 += odd ? (w2.z * xv2 + w2.x * xn2) : (w2.y * xv2 + w2.w * xn2);
            a3 += odd ? (w3.z * xv3 + w3.x * xn3) : (w3.y * xv3 + w3.w * xn3);
        }
        y[(size_t)b * 65536 + 4 * u0 + tid] = blp[0] + ((a0 + a1) + (a2 + a3));
    }
}

extern "C" void kernel_launch(void* const* d_in, const int* in_sizes, int n_in,
                              void* d_out, int out_size, void* d_ws, size_t ws_size,
                              hipStream_t stream) {
    const float* x      = (const float*)d_in[0];
    const float* enc_w0 = (const float*)d_in[1];
    const float* enc_w  = (const float*)d_in[2];   // (5,64,64,4)
    const float* enc_b  = (const float*)d_in[3];   // (6,64)
    const float* cb     = (const float*)d_in[4];   // (1024,64)
    const float* dec_w  = (const float*)d_in[5];   // (5,64,64,4) [in][out][k]
    const float* dec_wl = (const float*)d_in[6];   // (64,1,4)
    const float* dec_b  = (const float*)d_in[7];   // (5,64)
    const float* dec_bl = (const float*)d_in[8];   // (1,)
    float* y    = (float*)d_out;                   // (16,1,65536)
    float* z_e  = y + 1048576;                     // (16384,64)
    float* idsf = y + 2097152;                     // (16384,)

    // workspace overlay: A = 16.7M floats (67MB), Bf = 8.4M floats (33.6MB)
    float* A  = (float*)d_ws;
    float* Bf = A + 16777216;

    float*  encW  = y + 14 * 65536;
    ushort* Afrag = (ushort*)(encW + 81920);

    k_prepack_enc<<<dim3(320), 256, 0, stream>>>(enc_w, encW);
    k_prepack<<<dim3(320), 256, 0, stream>>>(dec_w, Afrag);

    // encoder (fp32, 8 blocks/CU)
    k_enc01<<<dim3(128, 16), 256, 0, stream>>>(x, enc_w0, enc_b, encW, enc_b + 64, A);
    k_enc_conv<<<dim3(64, 16), 256, 0, stream>>>(A,  encW + 1 * 16384, enc_b + 2 * 64, Bf, 16384, 8192, 0);
    k_enc_conv<<<dim3(32, 16), 256, 0, stream>>>(Bf, encW + 2 * 16384, enc_b + 3 * 64, A,  8192,  4096, 0);
    k_enc_conv<<<dim3(16, 16), 256, 0, stream>>>(A,  encW + 3 * 16384, enc_b + 4 * 64, Bf, 4096,  2048, 0);
    k_enc_conv<<<dim3(8, 16),  256, 0, stream>>>(Bf, encW + 4 * 16384, enc_b + 5 * 64, z_e, 2048, 1024, 1);
    // vector quantize -> g (padded bf16 [tok][d]) in A
    k_vq<<<256, 512, 0, stream>>>(z_e, cb, idsf, (ushort*)A);

    // decoder (bf16 MFMA v3.1, 1-wave k_dec2 blocks)
    k_dec2<<<dim3(64, 16),  64, 0, stream>>>((const ushort*)A,  Afrag + 0 * 16384, dec_b + 0 * 64, (ushort*)Bf, 1024);
    k_dec2<<<dim3(128, 16), 64, 0, stream>>>((const ushort*)Bf, Afrag + 1 * 16384, dec_b + 1 * 64, (ushort*)A,  2048);
    k_dec2<<<dim3(256, 16), 64, 0, stream>>>((const ushort*)A,  Afrag + 2 * 16384, dec_b + 2 * 64, (ushort*)Bf, 4096);
    k_dec2<<<dim3(512, 16), 64, 0, stream>>>((const ushort*)Bf, Afrag + 3 * 16384, dec_b + 3 * 64, (ushort*)A,  8192);
    // move layer-4 A-frags out of y (k_dec4y overwrites all of y)
    (void)hipMemcpyAsync(Bf, Afrag + 4 * 16384, 16384 * sizeof(ushort),
                         hipMemcpyDeviceToDevice, stream);
    k_dec4y<<<dim3(256, 16), 256, 0, stream>>>((const ushort*)A, (const ushort*)Bf,
                                               dec_w + 4 * 16384, dec_b + 4 * 64,
                                               dec_wl, dec_bl, y);
}